// Round 6
// baseline (994.056 us; speedup 1.0000x reference)
//
#include <hip/hip_runtime.h>
#include <hip/hip_bf16.h>
#include <math.h>

#define DIM 256
#define NB 4
#define LQ 1000
#define MLPD 512
#define LIN 21824
#define ROWS_X 4000
#define ROWS_SRC 87296
#define ATT_SCALE 0.17677669529663687f  /* 32^-0.5 */
#define LDK 72   /* padded LDS row (bf16 elems): 144 B, 16B-aligned */

typedef __hip_bfloat16 bf16;
typedef __attribute__((ext_vector_type(8))) short short8;
typedef __attribute__((ext_vector_type(4))) float floatx4;

__device__ __forceinline__ float rdv(const void* p, int f, size_t i){
    if (f) return ((const float*)p)[i];
    unsigned u = ((unsigned)((const unsigned short*)p)[i]) << 16;
    union { unsigned u; float f; } c; c.u = u; return c.f;
}
__device__ __forceinline__ short f2bs(float v){
    bf16 h = __float2bfloat16(v);
    return *reinterpret_cast<short*>(&h);
}

// ---------- dtype detect ----------
__global__ void detect_kernel(const void* __restrict__ x, int* __restrict__ flag){
    const unsigned short* u = (const unsigned short*)x;
    int t = threadIdx.x;
    bool hit = false;
    #pragma unroll
    for (int k = 0; k < 4; ++k) {
        unsigned short b = u[(t*4 + k)*2];
        union { unsigned u; float f; } c; c.u = ((unsigned)b) << 16;
        if (!(fabsf(c.f) <= 1000.f)) hit = true;
    }
    unsigned long long m = __ballot(hit);
    __shared__ unsigned long long red[4];
    if ((t & 63) == 0) red[t >> 6] = m;
    __syncthreads();
    if (t == 0) flag[0] = ((red[0]|red[1]|red[2]|red[3]) != 0ULL) ? 1 : 0;
}

__global__ void conv_kernel(const void* __restrict__ in, float* __restrict__ out,
                            int n, const int* __restrict__ flag){
    int f = flag[0];
    int i = blockIdx.x*256 + threadIdx.x;
    if (i < n) out[i] = rdv(in, f, i);
}

// ---------- fused small-param conversions ----------
struct PTab { const void* src[13]; float* dst[13]; int n[13]; };
__global__ void convs_kernel(PTab t, const int* __restrict__ flag){
    int f = flag[0];
    int j = blockIdx.y;
    int i = blockIdx.x*256 + threadIdx.x;
    if (i < t.n[j]) t.dst[j][i] = rdv(t.src[j], f, i);
}

// ---------- concat off_b|aw_b into oab[2][480] ----------
__global__ void catb_kernel(const void* __restrict__ offb, const void* __restrict__ awb,
                            const int* __restrict__ flag, float* __restrict__ oab){
    int f = flag[0];
    int layer = blockIdx.y;
    int idx = blockIdx.x*256 + threadIdx.x;
    if (idx >= 480) return;
    float v = (idx < 320) ? rdv(offb, f, (size_t)layer*320 + idx)
                          : rdv(awb,  f, (size_t)layer*160 + idx - 320);
    oab[layer*480 + idx] = v;
}

// ---------- weight transpose: W[b][K][N] -> Wt[b][ldout][K] bf16 at row offset ----------
__global__ void wtrans_kernel(const void* __restrict__ W, const int* __restrict__ flag,
                              short* __restrict__ Wt, int K, int N, int ldout, int rowoff){
    int f = flag[0];
    int b = blockIdx.z;
    __shared__ float t[32][33];
    int k0 = blockIdx.x*32, n0 = blockIdx.y*32;
    int tx = threadIdx.x & 31, ty = threadIdx.x >> 5;
    size_t base = (size_t)b * K * N;
    for (int i = ty; i < 32; i += 8) {
        int k = k0 + i, n = n0 + tx;
        t[i][tx] = (k < K && n < N) ? rdv(W, f, base + (size_t)k*N + n) : 0.f;
    }
    __syncthreads();
    for (int i = ty; i < 32; i += 8) {
        int n = n0 + i, k = k0 + tx;
        if (n < N && k < K)
            Wt[(size_t)b*ldout*K + (size_t)(rowoff+n)*K + k] = f2bs(t[tx][i]);
    }
}

// ---------- pe ----------
__global__ void pe_kernel(const float* __restrict__ cp, const float* __restrict__ pw,
                          const float* __restrict__ pb, float* __restrict__ pe){
    int row = blockIdx.x, t = threadIdx.x;
    float cx = cp[row*2], cy = cp[row*2+1];
    pe[(size_t)row*DIM + t] = cx*pw[t] + cy*pw[DIM+t] + pb[t];
}

// ---------- per-row stats of src ----------
__global__ void stats_kernel(const void* __restrict__ src, const int* __restrict__ flag,
                             float2* __restrict__ stats){
    int f = flag[0];
    int row = blockIdx.x, t = threadIdx.x;
    float v = rdv(src, f, (size_t)row*DIM + t);
    __shared__ float red[4];
    __shared__ float mean_s;
    float s = v;
    #pragma unroll
    for (int o = 32; o; o >>= 1) s += __shfl_down(s, o, 64);
    int lane = t & 63, wid = t >> 6;
    if (lane == 0) red[wid] = s;
    __syncthreads();
    if (t == 0) mean_s = (red[0]+red[1]+red[2]+red[3]) * (1.f/DIM);
    __syncthreads();
    float xm = v - mean_s;
    float s2 = xm*xm;
    #pragma unroll
    for (int o = 32; o; o >>= 1) s2 += __shfl_down(s2, o, 64);
    if (lane == 0) red[wid] = s2;
    __syncthreads();
    if (t == 0) {
        float var = (red[0]+red[1]+red[2]+red[3]) * (1.f/DIM);
        stats[row] = make_float2(mean_s, rsqrtf(var + 1e-5f));
    }
}

// ---------- LayerNorm: out = LN(in [+pre]) * g + b [+post] ----------
__global__ void ln_kernel(const float* __restrict__ in, const float* __restrict__ pre,
                          const float* __restrict__ post,
                          const float* __restrict__ g, const float* __restrict__ b,
                          float* __restrict__ out){
    int row = blockIdx.x, t = threadIdx.x;
    size_t base = (size_t)row * DIM;
    float v = in[base + t];
    if (pre) v += pre[base + t];
    __shared__ float red[4];
    __shared__ float mean_s, rstd_s;
    float s = v;
    #pragma unroll
    for (int o = 32; o; o >>= 1) s += __shfl_down(s, o, 64);
    int lane = t & 63, wid = t >> 6;
    if (lane == 0) red[wid] = s;
    __syncthreads();
    if (t == 0) mean_s = (red[0]+red[1]+red[2]+red[3]) * (1.f/DIM);
    __syncthreads();
    float xm = v - mean_s;
    float s2 = xm*xm;
    #pragma unroll
    for (int o = 32; o; o >>= 1) s2 += __shfl_down(s2, o, 64);
    if (lane == 0) red[wid] = s2;
    __syncthreads();
    if (t == 0) rstd_s = rsqrtf((red[0]+red[1]+red[2]+red[3]) * (1.f/DIM) + 1e-5f);
    __syncthreads();
    float ov = xm * rstd_s * g[t] + b[t];
    if (post) ov += post[base + t];
    out[base + t] = ov;
}

// ---------- MFMA GEMM 64x64: C = A @ Wt^T (+bias)(gelu?)(+res) ----------
__global__ __launch_bounds__(256) void mgemm_kernel(
    const void* __restrict__ Asrc,
    const short* __restrict__ Wt, const float* __restrict__ bias, const float* res,
    void* Cout, int M, int K, int N, int act, int amode, int cbf){
    __shared__ short As[64*LDK];
    __shared__ short Bs[64*LDK];
    int tid = threadIdx.x;
    int wave = tid >> 6, lane = tid & 63;
    int wm = wave >> 1, wn = wave & 1;
    int quad = lane >> 4, l16 = lane & 15;
    int row0 = blockIdx.x*64, col0 = blockIdx.y*64;
    floatx4 acc[2][2];
    #pragma unroll
    for (int i = 0; i < 2; ++i)
        #pragma unroll
        for (int j = 0; j < 2; ++j)
            acc[i][j] = (floatx4){0.f,0.f,0.f,0.f};

    int r  = tid >> 2;
    int kc = (tid & 3) * 16;
    int gr = row0 + r;
    int gc = col0 + r;
    const short8 z8 = {0,0,0,0,0,0,0,0};

    for (int k0 = 0; k0 < K; k0 += 64) {
        short8 a0 = z8, a1 = z8;
        if (gr < M) {
            if (amode == 2) {
                const short8* p = (const short8*)((const short*)Asrc + (size_t)gr*K + k0 + kc);
                a0 = p[0]; a1 = p[1];
            } else {
                const float4* p = (const float4*)((const float*)Asrc + (size_t)gr*K + k0 + kc);
                float4 x0 = p[0], x1 = p[1], x2 = p[2], x3 = p[3];
                a0[0]=f2bs(x0.x); a0[1]=f2bs(x0.y); a0[2]=f2bs(x0.z); a0[3]=f2bs(x0.w);
                a0[4]=f2bs(x1.x); a0[5]=f2bs(x1.y); a0[6]=f2bs(x1.z); a0[7]=f2bs(x1.w);
                a1[0]=f2bs(x2.x); a1[1]=f2bs(x2.y); a1[2]=f2bs(x2.z); a1[3]=f2bs(x2.w);
                a1[4]=f2bs(x3.x); a1[5]=f2bs(x3.y); a1[6]=f2bs(x3.z); a1[7]=f2bs(x3.w);
            }
        }
        *(short8*)&As[r*LDK + kc]     = a0;
        *(short8*)&As[r*LDK + kc + 8] = a1;
        short8 b0 = z8, b1 = z8;
        if (gc < N) {
            const short8* p = (const short8*)(Wt + (size_t)gc*K + k0 + kc);
            b0 = p[0]; b1 = p[1];
        }
        *(short8*)&Bs[r*LDK + kc]     = b0;
        *(short8*)&Bs[r*LDK + kc + 8] = b1;
        __syncthreads();
        #pragma unroll
        for (int kb = 0; kb < 64; kb += 32) {
            short8 af[2], bfr[2];
            #pragma unroll
            for (int mi = 0; mi < 2; ++mi)
                af[mi] = *(const short8*)&As[(wm*32 + mi*16 + l16)*LDK + kb + quad*8];
            #pragma unroll
            for (int ni = 0; ni < 2; ++ni)
                bfr[ni] = *(const short8*)&Bs[(wn*32 + ni*16 + l16)*LDK + kb + quad*8];
            #pragma unroll
            for (int mi = 0; mi < 2; ++mi)
                #pragma unroll
                for (int ni = 0; ni < 2; ++ni)
                    acc[mi][ni] = __builtin_amdgcn_mfma_f32_16x16x32_bf16(
                        af[mi], bfr[ni], acc[mi][ni], 0, 0, 0);
        }
        __syncthreads();
    }
    #pragma unroll
    for (int mi = 0; mi < 2; ++mi) {
        int rbase = row0 + wm*32 + mi*16 + quad*4;
        #pragma unroll
        for (int ni = 0; ni < 2; ++ni) {
            int c = col0 + wn*32 + ni*16 + l16;
            if (c >= N) continue;
            #pragma unroll
            for (int r2 = 0; r2 < 4; ++r2) {
                int rr = rbase + r2;
                if (rr >= M) continue;
                float v = acc[mi][ni][r2];
                if (bias) v += bias[c];
                if (act) v = 0.5f*v*(1.f + tanhf(0.7978845608028654f*(v + 0.044715f*v*v*v)));
                if (res) v += res[(size_t)rr*N + c];
                if (cbf) ((bf16*)Cout)[(size_t)rr*N + c] = __float2bfloat16(v);
                else     ((float*)Cout)[(size_t)rr*N + c] = v;
            }
        }
    }
}

// ---------- MFMA GEMM 128x128 with fused LN on A (value GEMM) ----------
__global__ __launch_bounds__(256) void mgemm128_kernel(
    const void* __restrict__ Asrc, const int* __restrict__ flag,
    const float2* __restrict__ stats, const float* __restrict__ g, const float* __restrict__ bvec,
    const short* __restrict__ Wt, const float* __restrict__ bias,
    bf16* __restrict__ C, int K, int N){
    __shared__ short As[128*LDK];
    __shared__ short Bs[128*LDK];
    __shared__ float gs[256], bs[256];
    int tid = threadIdx.x;
    int f = flag[0];
    int wave = tid >> 6, lane = tid & 63;
    int wm = wave >> 1, wn = wave & 1;
    int quad = lane >> 4, l16 = lane & 15;
    int row0 = blockIdx.x*128, col0 = blockIdx.y*128;
    if (tid < K) { gs[tid] = g[tid]; bs[tid] = bvec[tid]; }
    floatx4 acc[4][4];
    #pragma unroll
    for (int i = 0; i < 4; ++i)
        #pragma unroll
        for (int j = 0; j < 4; ++j)
            acc[i][j] = (floatx4){0.f,0.f,0.f,0.f};
    __syncthreads();

    for (int k0 = 0; k0 < K; k0 += 64) {
        #pragma unroll
        for (int i = 0; i < 2; ++i) {
            int idx = tid + i*256;
            int r = idx >> 2;
            int kc = (idx & 3) * 16;
            int gr = row0 + r;
            float2 st = stats[gr];
            float av[16];
            if (f) {
                const float4* p = (const float4*)((const float*)Asrc + (size_t)gr*K + k0 + kc);
                float4 x0 = p[0], x1 = p[1], x2 = p[2], x3 = p[3];
                av[0]=x0.x; av[1]=x0.y; av[2]=x0.z; av[3]=x0.w;
                av[4]=x1.x; av[5]=x1.y; av[6]=x1.z; av[7]=x1.w;
                av[8]=x2.x; av[9]=x2.y; av[10]=x2.z; av[11]=x2.w;
                av[12]=x3.x; av[13]=x3.y; av[14]=x3.z; av[15]=x3.w;
            } else {
                const short8* p = (const short8*)((const short*)Asrc + (size_t)gr*K + k0 + kc);
                short8 s0 = p[0], s1 = p[1];
                #pragma unroll
                for (int j = 0; j < 8; ++j) {
                    union { unsigned u; float f; } c0, c1;
                    c0.u = ((unsigned)(unsigned short)s0[j]) << 16;
                    c1.u = ((unsigned)(unsigned short)s1[j]) << 16;
                    av[j] = c0.f; av[8+j] = c1.f;
                }
            }
            short8 a0, a1;
            #pragma unroll
            for (int j = 0; j < 16; ++j) {
                float v = (av[j] - st.x) * st.y * gs[k0+kc+j] + bs[k0+kc+j];
                if (j < 8) a0[j] = f2bs(v); else a1[j-8] = f2bs(v);
            }
            *(short8*)&As[r*LDK + kc]     = a0;
            *(short8*)&As[r*LDK + kc + 8] = a1;
            int gc = col0 + r;
            const short8* pb = (const short8*)(Wt + (size_t)gc*K + k0 + kc);
            *(short8*)&Bs[r*LDK + kc]     = pb[0];
            *(short8*)&Bs[r*LDK + kc + 8] = pb[1];
        }
        __syncthreads();
        #pragma unroll
        for (int kb = 0; kb < 64; kb += 32) {
            short8 af[4], bfr[4];
            #pragma unroll
            for (int mi = 0; mi < 4; ++mi)
                af[mi] = *(const short8*)&As[(wm*64 + mi*16 + l16)*LDK + kb + quad*8];
            #pragma unroll
            for (int ni = 0; ni < 4; ++ni)
                bfr[ni] = *(const short8*)&Bs[(wn*64 + ni*16 + l16)*LDK + kb + quad*8];
            #pragma unroll
            for (int mi = 0; mi < 4; ++mi)
                #pragma unroll
                for (int ni = 0; ni < 4; ++ni)
                    acc[mi][ni] = __builtin_amdgcn_mfma_f32_16x16x32_bf16(
                        af[mi], bfr[ni], acc[mi][ni], 0, 0, 0);
        }
        __syncthreads();
    }
    #pragma unroll
    for (int mi = 0; mi < 4; ++mi) {
        int rbase = row0 + wm*64 + mi*16 + quad*4;
        #pragma unroll
        for (int ni = 0; ni < 4; ++ni) {
            int c = col0 + wn*64 + ni*16 + l16;
            float bv = bias[c];
            #pragma unroll
            for (int r2 = 0; r2 < 4; ++r2)
                C[(size_t)(rbase + r2)*N + c] = __float2bfloat16(acc[mi][ni][r2] + bv);
        }
    }
}

// ---------- self-attention v3: 2 queries/thread, batched-8 online softmax ----------
// grid (16, 32): block covers 64 queries (qa=qp, qb=qp+32), 8 k-slices/query.
__global__ __launch_bounds__(256) void attn3_kernel(const bf16* __restrict__ qkv,
                                                    float* __restrict__ out){
    int nh = blockIdx.y; int n = nh >> 3, h = nh & 7;
    int tid = threadIdx.x;
    int sub = tid & 7, qp = tid >> 3;          // qp 0..31
    int qa = blockIdx.x*64 + qp;
    int qb = qa + 32;
    bool oka = qa < LQ, okb = qb < LQ;
    __shared__ float Ks[64][36];
    __shared__ float Vs[64][36];
    const size_t base = (size_t)n * LQ * 768;
    float qra[32], qrb[32];
    #pragma unroll
    for (int d = 0; d < 32; ++d) { qra[d] = 0.f; qrb[d] = 0.f; }
    if (oka) {
        const short8* p = (const short8*)(qkv + base + (size_t)qa*768 + h*32);
        #pragma unroll
        for (int c = 0; c < 4; ++c) {
            short8 s = p[c];
            #pragma unroll
            for (int j = 0; j < 8; ++j) {
                union { unsigned u; float f; } cv; cv.u = ((unsigned)(unsigned short)s[j]) << 16;
                qra[c*8+j] = cv.f * ATT_SCALE;
            }
        }
    }
    if (okb) {
        const short8* p = (const short8*)(qkv + base + (size_t)qb*768 + h*32);
        #pragma unroll
        for (int c = 0; c < 4; ++c) {
            short8 s = p[c];
            #pragma unroll
            for (int j = 0; j < 8; ++j) {
                union { unsigned u; float f; } cv; cv.u = ((unsigned)(unsigned short)s[j]) << 16;
                qrb[c*8+j] = cv.f * ATT_SCALE;
            }
        }
    }
    float ma = -3.0e38f, la = 0.f, mb = -3.0e38f, lb = 0.f;
    float oa[32], ob[32];
    #pragma unroll
    for (int d = 0; d < 32; ++d) { oa[d] = 0.f; ob[d] = 0.f; }

    for (int j0 = 0; j0 < LQ; j0 += 64) {
        int cnt = min(64, LQ - j0);     // 64 or 40 (multiple of 8)
        for (int i = tid; i < cnt*32; i += 256) {
            int jj = i >> 5, d = i & 31;
            size_t rb = base + (size_t)(j0+jj)*768 + h*32 + d;
            Ks[jj][d] = __bfloat162float(qkv[rb + 256]);
            Vs[jj][d] = __bfloat162float(qkv[rb + 512]);
        }
        __syncthreads();
        int steps = cnt >> 3;           // 8 or 5
        float sca[8], scb[8];
        #pragma unroll
        for (int t = 0; t < 8; ++t) {
            sca[t] = -3.0e38f; scb[t] = -3.0e38f;
            if (t < steps) {
                const float4* kr = (const float4*)&Ks[t*8 + sub][0];
                float sa = 0.f, sb = 0.f;
                #pragma unroll
                for (int w = 0; w < 8; ++w) {
                    float4 kv = kr[w];
                    sa = fmaf(qra[4*w],   kv.x, sa); sb = fmaf(qrb[4*w],   kv.x, sb);
                    sa = fmaf(qra[4*w+1], kv.y, sa); sb = fmaf(qrb[4*w+1], kv.y, sb);
                    sa = fmaf(qra[4*w+2], kv.z, sa); sb = fmaf(qrb[4*w+2], kv.z, sb);
                    sa = fmaf(qra[4*w+3], kv.w, sa); sb = fmaf(qrb[4*w+3], kv.w, sb);
                }
                sca[t] = sa; scb[t] = sb;
            }
        }
        float tma = sca[0], tmb = scb[0];
        #pragma unroll
        for (int t = 1; t < 8; ++t) { tma = fmaxf(tma, sca[t]); tmb = fmaxf(tmb, scb[t]); }
        float mna = fmaxf(ma, tma), mnb = fmaxf(mb, tmb);
        float c0a = __expf(ma - mna), c0b = __expf(mb - mnb);
        float pa[8], pb[8], spa = 0.f, spb = 0.f;
        #pragma unroll
        for (int t = 0; t < 8; ++t) {
            pa[t] = __expf(sca[t] - mna); spa += pa[t];
            pb[t] = __expf(scb[t] - mnb); spb += pb[t];
        }
        la = la*c0a + spa; lb = lb*c0b + spb;
        ma = mna; mb = mnb;
        #pragma unroll
        for (int w = 0; w < 8; ++w) {
            float4 oa4 = *(float4*)&oa[w*4];
            float4 ob4 = *(float4*)&ob[w*4];
            oa4.x *= c0a; oa4.y *= c0a; oa4.z *= c0a; oa4.w *= c0a;
            ob4.x *= c0b; ob4.y *= c0b; ob4.z *= c0b; ob4.w *= c0b;
            #pragma unroll
            for (int t = 0; t < 8; ++t) {
                float4 vv = *(const float4*)&Vs[t*8 + sub][w*4];
                oa4.x = fmaf(pa[t], vv.x, oa4.x); ob4.x = fmaf(pb[t], vv.x, ob4.x);
                oa4.y = fmaf(pa[t], vv.y, oa4.y); ob4.y = fmaf(pb[t], vv.y, ob4.y);
                oa4.z = fmaf(pa[t], vv.z, oa4.z); ob4.z = fmaf(pb[t], vv.z, ob4.z);
                oa4.w = fmaf(pa[t], vv.w, oa4.w); ob4.w = fmaf(pb[t], vv.w, ob4.w);
            }
            *(float4*)&oa[w*4] = oa4;
            *(float4*)&ob[w*4] = ob4;
        }
        __syncthreads();
    }
    // combine 8 k-slices (8 consecutive lanes per query)
    #pragma unroll
    for (int off = 1; off < 8; off <<= 1) {
        float moa = __shfl_xor(ma, off, 64), loa = __shfl_xor(la, off, 64);
        float mob = __shfl_xor(mb, off, 64), lob = __shfl_xor(lb, off, 64);
        float mna = fmaxf(ma, moa), mnb = fmaxf(mb, mob);
        float aa = __expf(ma - mna), ba = __expf(moa - mna);
        float ab = __expf(mb - mnb), bb = __expf(mob - mnb);
        la = la*aa + loa*ba; lb = lb*ab + lob*bb;
        #pragma unroll
        for (int d = 0; d < 32; ++d) {
            float xa = __shfl_xor(oa[d], off, 64);
            float xb = __shfl_xor(ob[d], off, 64);
            oa[d] = oa[d]*aa + xa*ba;
            ob[d] = ob[d]*ab + xb*bb;
        }
        ma = mna; mb = mnb;
    }
    float va0=0.f,va1=0.f,va2=0.f,va3=0.f, vb0=0.f,vb1=0.f,vb2=0.f,vb3=0.f;
    #pragma unroll
    for (int c = 0; c < 8; ++c) {
        if (sub == c) {
            va0 = oa[c*4]; va1 = oa[c*4+1]; va2 = oa[c*4+2]; va3 = oa[c*4+3];
            vb0 = ob[c*4]; vb1 = ob[c*4+1]; vb2 = ob[c*4+2]; vb3 = ob[c*4+3];
        }
    }
    if (oka) {
        float inv = 1.f / la;
        float4 ov = { va0*inv, va1*inv, va2*inv, va3*inv };
        *(float4*)&out[((size_t)n*LQ + qa)*256 + h*32 + sub*4] = ov;
    }
    if (okb) {
        float inv = 1.f / lb;
        float4 ov = { vb0*inv, vb1*inv, vb2*inv, vb3*inv };
        *(float4*)&out[((size_t)n*LQ + qb)*256 + h*32 + sub*4] = ov;
    }
}

// ---------- deformable sampling with fused aw-softmax + shuffle broadcasts ----------
__global__ __launch_bounds__(256) void sample2_kernel(
        const bf16* __restrict__ value, const float* __restrict__ offaw,
        const float* __restrict__ cp, float* __restrict__ out){
    int nq = blockIdx.x;
    int n = nq / LQ;
    int d = threadIdx.x & 31, h = threadIdx.x >> 5;
    float cx = cp[nq*2], cy = cp[nq*2+1];
    const float* rowp = offaw + (size_t)nq*480;
    float o0 = rowp[h*40 + d];                       // offsets 0..31
    float o1 = (d < 8) ? rowp[h*40 + 32 + d] : 0.f;  // offsets 32..39
    // softmax over 20 logits held in lanes d<20
    float logit = (d < 20) ? rowp[320 + h*20 + d] : -3.0e38f;
    float mx = logit;
    #pragma unroll
    for (int off = 16; off; off >>= 1) mx = fmaxf(mx, __shfl_xor(mx, off, 32));
    float p = (d < 20) ? __expf(logit - mx) : 0.f;
    float sm = p;
    #pragma unroll
    for (int off = 16; off; off >>= 1) sm += __shfl_xor(sm, off, 32);
    p *= (1.f / sm);

    const int HW[5] = {128,64,32,16,8};
    const int ST[5] = {0,16384,20480,21504,21760};
    float acc = 0.f;
    #pragma unroll
    for (int l = 0; l < 5; ++l) {
        int hw = HW[l];
        float fhw = (float)hw;
        size_t vb = ((size_t)n*LIN + ST[l]) * 256 + h*32 + d;
        #pragma unroll
        for (int pi = 0; pi < 4; ++pi) {
            const int idx = l*4 + pi;
            float w  = __shfl(p, idx, 32);
            float ox = (2*idx < 32)   ? __shfl(o0, 2*idx, 32)   : __shfl(o1, 2*idx-32, 32);
            float oy = (2*idx+1 < 32) ? __shfl(o0, 2*idx+1, 32) : __shfl(o1, 2*idx+1-32, 32);
            float gx = cx*fhw + ox - 0.5f;
            float gy = cy*fhw + oy - 0.5f;
            float x0f = floorf(gx), y0f = floorf(gy);
            float lx = gx - x0f, ly = gy - y0f;
            int x0 = (int)x0f, y0 = (int)y0f;
            float s = 0.f;
            if ((unsigned)y0     < (unsigned)hw && (unsigned)x0     < (unsigned)hw)
                s += (1.f-ly)*(1.f-lx)*__bfloat162float(value[vb + (size_t)(y0*hw + x0)*256]);
            if ((unsigned)y0     < (unsigned)hw && (unsigned)(x0+1) < (unsigned)hw)
                s += (1.f-ly)*lx      *__bfloat162float(value[vb + (size_t)(y0*hw + x0+1)*256]);
            if ((unsigned)(y0+1) < (unsigned)hw && (unsigned)x0     < (unsigned)hw)
                s += ly*(1.f-lx)      *__bfloat162float(value[vb + (size_t)((y0+1)*hw + x0)*256]);
            if ((unsigned)(y0+1) < (unsigned)hw && (unsigned)(x0+1) < (unsigned)hw)
                s += ly*lx            *__bfloat162float(value[vb + (size_t)((y0+1)*hw + x0+1)*256]);
            acc += w * s;
        }
    }
    out[(size_t)nq*256 + h*32 + d] = acc;
}

// ---------- final store ----------
__global__ void final_kernel(const float* __restrict__ in, void* __restrict__ out,
                             int n, const int* __restrict__ flag){
    int f = flag[0];
    int i = blockIdx.x*256 + threadIdx.x;
    if (i >= n) return;
    float v = in[i];
    if (!isfinite(v)) v = 0.f;
    if (f) ((float*)out)[i] = v;
    else   ((bf16*)out)[i] = __float2bfloat16(v);
}

extern "C" void kernel_launch(void* const* d_in, const int* in_sizes, int n_in,
                              void* d_out, int out_size, void* d_ws, size_t ws_size,
                              hipStream_t stream){
    const void* x_raw  = d_in[0];
    const void* src    = d_in[1];
    const void* cp_raw = d_in[2];
    char* ws = (char*)d_ws;
    size_t off = 0;
    auto alloc = [&](size_t bytes){ size_t p = off; off += (bytes + 255) & ~(size_t)255; return p; };
    int*   flag  = (int*)(ws + alloc(256));
    float* xf    = (float*)(ws + alloc((size_t)ROWS_X*DIM*4));
    float* pe    = (float*)(ws + alloc((size_t)ROWS_X*DIM*4));
    float* nbuf  = (float*)(ws + alloc((size_t)ROWS_X*DIM*4));
    float* tmp   = (float*)(ws + alloc((size_t)ROWS_X*DIM*4));
    bf16*  qkv   = (bf16*)(ws + alloc((size_t)ROWS_X*768*2));
    bf16*  ffh   = (bf16*)(ws + alloc((size_t)ROWS_X*MLPD*2));
    float* offaw = (float*)(ws + alloc((size_t)ROWS_X*480*4));
    float2* stats = (float2*)(ws + alloc((size_t)ROWS_SRC*8));
    float* cpf   = (float*)(ws + alloc((size_t)ROWS_X*2*4));
    float* oab   = (float*)(ws + alloc((size_t)2*480*4));
    // small fp32 params (13): pos_w,pos_b,ln1_g,ln1_b,out_b,ln2_g,ln2_b,val_b,op_b,ln3_g,ln3_b,ff_b1,ff_b2
    const int sidx[13] = {5,6,7,8,11,12,13,19,21,22,23,25,27};
    const int ssz[13]  = {512,256,512,512,512,512,512,512,512,512,512,1024,512};
    float* sp[13];
    for (int j = 0; j < 13; ++j) sp[j] = (float*)(ws + alloc((size_t)ssz[j]*4));
    short* qkvT = (short*)(ws + alloc((size_t)2*768*256*2));
    short* outT = (short*)(ws + alloc((size_t)2*256*256*2));
    short* oawT = (short*)(ws + alloc((size_t)2*480*256*2));
    short* valT = (short*)(ws + alloc((size_t)2*256*256*2));
    short* opT  = (short*)(ws + alloc((size_t)2*256*256*2));
    short* ff1T = (short*)(ws + alloc((size_t)2*512*256*2));
    short* ff2T = (short*)(ws + alloc((size_t)2*256*512*2));
    bf16*  val  = (bf16*)(ws + alloc((size_t)ROWS_SRC*DIM*2));
    (void)ws_size; (void)in_sizes; (void)n_in; (void)out_size;

    detect_kernel<<<1, 256, 0, stream>>>(x_raw, flag);
    conv_kernel<<<(ROWS_X*DIM+255)/256, 256, 0, stream>>>(x_raw, xf, ROWS_X*DIM, flag);
    conv_kernel<<<(ROWS_X*2+255)/256, 256, 0, stream>>>(cp_raw, cpf, ROWS_X*2, flag);
    PTab pt;
    for (int j = 0; j < 13; ++j) { pt.src[j] = d_in[sidx[j]]; pt.dst[j] = sp[j]; pt.n[j] = ssz[j]; }
    convs_kernel<<<dim3(4,13), 256, 0, stream>>>(pt, flag);
    catb_kernel<<<dim3(2,2), 256, 0, stream>>>(d_in[15], d_in[17], flag, oab);
    wtrans_kernel<<<dim3(8,24,2), 256, 0, stream>>>(d_in[9],  flag, qkvT, 256, 768, 768, 0);
    wtrans_kernel<<<dim3(8,8,2),  256, 0, stream>>>(d_in[10], flag, outT, 256, 256, 256, 0);
    wtrans_kernel<<<dim3(8,10,2), 256, 0, stream>>>(d_in[14], flag, oawT, 256, 320, 480, 0);
    wtrans_kernel<<<dim3(8,5,2),  256, 0, stream>>>(d_in[16], flag, oawT, 256, 160, 480, 320);
    wtrans_kernel<<<dim3(8,8,2),  256, 0, stream>>>(d_in[18], flag, valT, 256, 256, 256, 0);
    wtrans_kernel<<<dim3(8,8,2),  256, 0, stream>>>(d_in[20], flag, opT,  256, 256, 256, 0);
    wtrans_kernel<<<dim3(8,16,2), 256, 0, stream>>>(d_in[24], flag, ff1T, 256, 512, 512, 0);
    wtrans_kernel<<<dim3(16,8,2), 256, 0, stream>>>(d_in[26], flag, ff2T, 512, 256, 256, 0);

    float* pos_w = sp[0];  float* pos_b = sp[1];
    float* ln1_g = sp[2];  float* ln1_b = sp[3];
    float* out_b = sp[4];
    float* ln2_g = sp[5];  float* ln2_b = sp[6];
    float* val_b = sp[7];  float* op_b  = sp[8];
    float* ln3_g = sp[9];  float* ln3_b = sp[10];
    float* ff_b1 = sp[11]; float* ff_b2 = sp[12];

    pe_kernel<<<ROWS_X, 256, 0, stream>>>(cpf, pos_w, pos_b, pe);
    stats_kernel<<<ROWS_SRC, 256, 0, stream>>>(src, flag, stats);

    int gmx = (ROWS_X + 63) / 64;   // 63
    for (int i = 0; i < 2; ++i) {
        // --- self attention ---
        ln_kernel<<<ROWS_X, 256, 0, stream>>>(xf, pe, nullptr, ln1_g + i*DIM, ln1_b + i*DIM, nbuf);
        mgemm_kernel<<<dim3(gmx,12), 256, 0, stream>>>(
            nbuf, qkvT + (size_t)i*768*256, nullptr, nullptr, qkv, ROWS_X, 256, 768, 0, 0, 1);
        attn3_kernel<<<dim3(16,32), 256, 0, stream>>>(qkv, tmp);
        mgemm_kernel<<<dim3(gmx,4), 256, 0, stream>>>(
            tmp, outT + (size_t)i*256*256, out_b + i*DIM, xf, xf, ROWS_X, 256, 256, 0, 0, 0);
        // --- deformable cross attention ---
        mgemm128_kernel<<<dim3(ROWS_SRC/128, 2), 256, 0, stream>>>(
            src, flag, stats, ln2_g + i*DIM, ln2_b + i*DIM,
            valT + (size_t)i*256*256, val_b + i*DIM, val, 256, 256);
        ln_kernel<<<ROWS_X, 256, 0, stream>>>(xf, nullptr, pe, ln2_g + i*DIM, ln2_b + i*DIM, nbuf);
        mgemm_kernel<<<dim3(gmx,8), 256, 0, stream>>>(
            nbuf, oawT + (size_t)i*480*256, oab + i*480, nullptr, offaw, ROWS_X, 256, 480, 0, 0, 0);
        sample2_kernel<<<ROWS_X, 256, 0, stream>>>(val, offaw, cpf, tmp);
        mgemm_kernel<<<dim3(gmx,4), 256, 0, stream>>>(
            tmp, opT + (size_t)i*256*256, op_b + i*DIM, xf, xf, ROWS_X, 256, 256, 0, 0, 0);
        // --- feedforward ---
        ln_kernel<<<ROWS_X, 256, 0, stream>>>(xf, nullptr, nullptr, ln3_g + i*DIM, ln3_b + i*DIM, nbuf);
        mgemm_kernel<<<dim3(gmx,8), 256, 0, stream>>>(
            nbuf, ff1T + (size_t)i*512*256, ff_b1 + i*MLPD, nullptr, ffh, ROWS_X, 256, 512, 1, 0, 1);
        mgemm_kernel<<<dim3(gmx,4), 256, 0, stream>>>(
            ffh, ff2T + (size_t)i*256*512, ff_b2 + i*DIM, xf, xf, ROWS_X, 512, 256, 0, 2, 0);
    }
    final_kernel<<<(ROWS_X*DIM+255)/256, 256, 0, stream>>>(xf, d_out, ROWS_X*DIM, flag);
}

// Round 7
// 864.810 us; speedup vs baseline: 1.1495x; 1.1495x over previous
//
#include <hip/hip_runtime.h>
#include <hip/hip_bf16.h>
#include <math.h>

#define DIM 256
#define NB 4
#define LQ 1000
#define MLPD 512
#define LIN 21824
#define ROWS_X 4000
#define ROWS_SRC 87296
#define ATT_SCALE 0.17677669529663687f  /* 32^-0.5 */
#define LDK 72   /* padded LDS row (bf16 elems): 144 B, 16B-aligned */

typedef __hip_bfloat16 bf16;
typedef __attribute__((ext_vector_type(8))) short short8;
typedef __attribute__((ext_vector_type(4))) float floatx4;

__device__ __forceinline__ float rdv(const void* p, int f, size_t i){
    if (f) return ((const float*)p)[i];
    unsigned u = ((unsigned)((const unsigned short*)p)[i]) << 16;
    union { unsigned u; float f; } c; c.u = u; return c.f;
}
__device__ __forceinline__ short f2bs(float v){
    bf16 h = __float2bfloat16(v);
    return *reinterpret_cast<short*>(&h);
}
__device__ __forceinline__ float bs2f(short s){
    union { unsigned u; float f; } c; c.u = ((unsigned)(unsigned short)s) << 16; return c.f;
}

// ---------- dtype detect ----------
__global__ void detect_kernel(const void* __restrict__ x, int* __restrict__ flag){
    const unsigned short* u = (const unsigned short*)x;
    int t = threadIdx.x;
    bool hit = false;
    #pragma unroll
    for (int k = 0; k < 4; ++k) {
        unsigned short b = u[(t*4 + k)*2];
        union { unsigned u; float f; } c; c.u = ((unsigned)b) << 16;
        if (!(fabsf(c.f) <= 1000.f)) hit = true;
    }
    unsigned long long m = __ballot(hit);
    __shared__ unsigned long long red[4];
    if ((t & 63) == 0) red[t >> 6] = m;
    __syncthreads();
    if (t == 0) flag[0] = ((red[0]|red[1]|red[2]|red[3]) != 0ULL) ? 1 : 0;
}

__global__ void conv_kernel(const void* __restrict__ in, float* __restrict__ out,
                            int n, const int* __restrict__ flag){
    int f = flag[0];
    int i = blockIdx.x*256 + threadIdx.x;
    if (i < n) out[i] = rdv(in, f, i);
}

// ---------- fused small-param conversions ----------
struct PTab { const void* src[13]; float* dst[13]; int n[13]; };
__global__ void convs_kernel(PTab t, const int* __restrict__ flag){
    int f = flag[0];
    int j = blockIdx.y;
    int i = blockIdx.x*256 + threadIdx.x;
    if (i < t.n[j]) t.dst[j][i] = rdv(t.src[j], f, i);
}

// ---------- concat off_b|aw_b into oab[2][480] ----------
__global__ void catb_kernel(const void* __restrict__ offb, const void* __restrict__ awb,
                            const int* __restrict__ flag, float* __restrict__ oab){
    int f = flag[0];
    int layer = blockIdx.y;
    int idx = blockIdx.x*256 + threadIdx.x;
    if (idx >= 480) return;
    float v = (idx < 320) ? rdv(offb, f, (size_t)layer*320 + idx)
                          : rdv(awb,  f, (size_t)layer*160 + idx - 320);
    oab[layer*480 + idx] = v;
}

// ---------- weight transpose: W[b][K][N] -> Wt[b][ldout][K] bf16 at row offset ----------
__global__ void wtrans_kernel(const void* __restrict__ W, const int* __restrict__ flag,
                              short* __restrict__ Wt, int K, int N, int ldout, int rowoff){
    int f = flag[0];
    int b = blockIdx.z;
    __shared__ float t[32][33];
    int k0 = blockIdx.x*32, n0 = blockIdx.y*32;
    int tx = threadIdx.x & 31, ty = threadIdx.x >> 5;
    size_t base = (size_t)b * K * N;
    for (int i = ty; i < 32; i += 8) {
        int k = k0 + i, n = n0 + tx;
        t[i][tx] = (k < K && n < N) ? rdv(W, f, base + (size_t)k*N + n) : 0.f;
    }
    __syncthreads();
    for (int i = ty; i < 32; i += 8) {
        int n = n0 + i, k = k0 + tx;
        if (n < N && k < K)
            Wt[(size_t)b*ldout*K + (size_t)(rowoff+n)*K + k] = f2bs(t[tx][i]);
    }
}

// ---------- pe ----------
__global__ void pe_kernel(const float* __restrict__ cp, const float* __restrict__ pw,
                          const float* __restrict__ pb, float* __restrict__ pe){
    int row = blockIdx.x, t = threadIdx.x;
    float cx = cp[row*2], cy = cp[row*2+1];
    pe[(size_t)row*DIM + t] = cx*pw[t] + cy*pw[DIM+t] + pb[t];
}

// ---------- per-row stats of src ----------
__global__ void stats_kernel(const void* __restrict__ src, const int* __restrict__ flag,
                             float2* __restrict__ stats){
    int f = flag[0];
    int row = blockIdx.x, t = threadIdx.x;
    float v = rdv(src, f, (size_t)row*DIM + t);
    __shared__ float red[4];
    __shared__ float mean_s;
    float s = v;
    #pragma unroll
    for (int o = 32; o; o >>= 1) s += __shfl_down(s, o, 64);
    int lane = t & 63, wid = t >> 6;
    if (lane == 0) red[wid] = s;
    __syncthreads();
    if (t == 0) mean_s = (red[0]+red[1]+red[2]+red[3]) * (1.f/DIM);
    __syncthreads();
    float xm = v - mean_s;
    float s2 = xm*xm;
    #pragma unroll
    for (int o = 32; o; o >>= 1) s2 += __shfl_down(s2, o, 64);
    if (lane == 0) red[wid] = s2;
    __syncthreads();
    if (t == 0) {
        float var = (red[0]+red[1]+red[2]+red[3]) * (1.f/DIM);
        stats[row] = make_float2(mean_s, rsqrtf(var + 1e-5f));
    }
}

// ---------- LayerNorm: out = LN(in [+pre]) * g + b [+post] ----------
__global__ void ln_kernel(const float* __restrict__ in, const float* __restrict__ pre,
                          const float* __restrict__ post,
                          const float* __restrict__ g, const float* __restrict__ b,
                          float* __restrict__ out){
    int row = blockIdx.x, t = threadIdx.x;
    size_t base = (size_t)row * DIM;
    float v = in[base + t];
    if (pre) v += pre[base + t];
    __shared__ float red[4];
    __shared__ float mean_s, rstd_s;
    float s = v;
    #pragma unroll
    for (int o = 32; o; o >>= 1) s += __shfl_down(s, o, 64);
    int lane = t & 63, wid = t >> 6;
    if (lane == 0) red[wid] = s;
    __syncthreads();
    if (t == 0) mean_s = (red[0]+red[1]+red[2]+red[3]) * (1.f/DIM);
    __syncthreads();
    float xm = v - mean_s;
    float s2 = xm*xm;
    #pragma unroll
    for (int o = 32; o; o >>= 1) s2 += __shfl_down(s2, o, 64);
    if (lane == 0) red[wid] = s2;
    __syncthreads();
    if (t == 0) rstd_s = rsqrtf((red[0]+red[1]+red[2]+red[3]) * (1.f/DIM) + 1e-5f);
    __syncthreads();
    float ov = xm * rstd_s * g[t] + b[t];
    if (post) ov += post[base + t];
    out[base + t] = ov;
}

// ---------- MFMA GEMM 64x64: C = A @ Wt^T (+bias)(gelu?)(+res) ----------
__global__ __launch_bounds__(256) void mgemm_kernel(
    const void* __restrict__ Asrc,
    const short* __restrict__ Wt, const float* __restrict__ bias, const float* res,
    void* Cout, int M, int K, int N, int act, int amode, int cbf){
    __shared__ short As[64*LDK];
    __shared__ short Bs[64*LDK];
    int tid = threadIdx.x;
    int wave = tid >> 6, lane = tid & 63;
    int wm = wave >> 1, wn = wave & 1;
    int quad = lane >> 4, l16 = lane & 15;
    int row0 = blockIdx.x*64, col0 = blockIdx.y*64;
    floatx4 acc[2][2];
    #pragma unroll
    for (int i = 0; i < 2; ++i)
        #pragma unroll
        for (int j = 0; j < 2; ++j)
            acc[i][j] = (floatx4){0.f,0.f,0.f,0.f};

    int r  = tid >> 2;
    int kc = (tid & 3) * 16;
    int gr = row0 + r;
    int gc = col0 + r;
    const short8 z8 = {0,0,0,0,0,0,0,0};

    for (int k0 = 0; k0 < K; k0 += 64) {
        short8 a0 = z8, a1 = z8;
        if (gr < M) {
            if (amode == 2) {
                const short8* p = (const short8*)((const short*)Asrc + (size_t)gr*K + k0 + kc);
                a0 = p[0]; a1 = p[1];
            } else {
                const float4* p = (const float4*)((const float*)Asrc + (size_t)gr*K + k0 + kc);
                float4 x0 = p[0], x1 = p[1], x2 = p[2], x3 = p[3];
                a0[0]=f2bs(x0.x); a0[1]=f2bs(x0.y); a0[2]=f2bs(x0.z); a0[3]=f2bs(x0.w);
                a0[4]=f2bs(x1.x); a0[5]=f2bs(x1.y); a0[6]=f2bs(x1.z); a0[7]=f2bs(x1.w);
                a1[0]=f2bs(x2.x); a1[1]=f2bs(x2.y); a1[2]=f2bs(x2.z); a1[3]=f2bs(x2.w);
                a1[4]=f2bs(x3.x); a1[5]=f2bs(x3.y); a1[6]=f2bs(x3.z); a1[7]=f2bs(x3.w);
            }
        }
        *(short8*)&As[r*LDK + kc]     = a0;
        *(short8*)&As[r*LDK + kc + 8] = a1;
        short8 b0 = z8, b1 = z8;
        if (gc < N) {
            const short8* p = (const short8*)(Wt + (size_t)gc*K + k0 + kc);
            b0 = p[0]; b1 = p[1];
        }
        *(short8*)&Bs[r*LDK + kc]     = b0;
        *(short8*)&Bs[r*LDK + kc + 8] = b1;
        __syncthreads();
        #pragma unroll
        for (int kb = 0; kb < 64; kb += 32) {
            short8 af[2], bfr[2];
            #pragma unroll
            for (int mi = 0; mi < 2; ++mi)
                af[mi] = *(const short8*)&As[(wm*32 + mi*16 + l16)*LDK + kb + quad*8];
            #pragma unroll
            for (int ni = 0; ni < 2; ++ni)
                bfr[ni] = *(const short8*)&Bs[(wn*32 + ni*16 + l16)*LDK + kb + quad*8];
            #pragma unroll
            for (int mi = 0; mi < 2; ++mi)
                #pragma unroll
                for (int ni = 0; ni < 2; ++ni)
                    acc[mi][ni] = __builtin_amdgcn_mfma_f32_16x16x32_bf16(
                        af[mi], bfr[ni], acc[mi][ni], 0, 0, 0);
        }
        __syncthreads();
    }
    #pragma unroll
    for (int mi = 0; mi < 2; ++mi) {
        int rbase = row0 + wm*32 + mi*16 + quad*4;
        #pragma unroll
        for (int ni = 0; ni < 2; ++ni) {
            int c = col0 + wn*32 + ni*16 + l16;
            if (c >= N) continue;
            #pragma unroll
            for (int r2 = 0; r2 < 4; ++r2) {
                int rr = rbase + r2;
                if (rr >= M) continue;
                float v = acc[mi][ni][r2];
                if (bias) v += bias[c];
                if (act) v = 0.5f*v*(1.f + tanhf(0.7978845608028654f*(v + 0.044715f*v*v*v)));
                if (res) v += res[(size_t)rr*N + c];
                if (cbf) ((bf16*)Cout)[(size_t)rr*N + c] = __float2bfloat16(v);
                else     ((float*)Cout)[(size_t)rr*N + c] = v;
            }
        }
    }
}

// ---------- MFMA GEMM 128x128 with fused LN on A (value GEMM) ----------
__global__ __launch_bounds__(256) void mgemm128_kernel(
    const void* __restrict__ Asrc, const int* __restrict__ flag,
    const float2* __restrict__ stats, const float* __restrict__ g, const float* __restrict__ bvec,
    const short* __restrict__ Wt, const float* __restrict__ bias,
    bf16* __restrict__ C, int K, int N){
    __shared__ short As[128*LDK];
    __shared__ short Bs[128*LDK];
    __shared__ float gs[256], bs[256];
    int tid = threadIdx.x;
    int f = flag[0];
    int wave = tid >> 6, lane = tid & 63;
    int wm = wave >> 1, wn = wave & 1;
    int quad = lane >> 4, l16 = lane & 15;
    int row0 = blockIdx.x*128, col0 = blockIdx.y*128;
    if (tid < K) { gs[tid] = g[tid]; bs[tid] = bvec[tid]; }
    floatx4 acc[4][4];
    #pragma unroll
    for (int i = 0; i < 4; ++i)
        #pragma unroll
        for (int j = 0; j < 4; ++j)
            acc[i][j] = (floatx4){0.f,0.f,0.f,0.f};
    __syncthreads();

    for (int k0 = 0; k0 < K; k0 += 64) {
        #pragma unroll
        for (int i = 0; i < 2; ++i) {
            int idx = tid + i*256;
            int r = idx >> 2;
            int kc = (idx & 3) * 16;
            int gr = row0 + r;
            float2 st = stats[gr];
            float av[16];
            if (f) {
                const float4* p = (const float4*)((const float*)Asrc + (size_t)gr*K + k0 + kc);
                float4 x0 = p[0], x1 = p[1], x2 = p[2], x3 = p[3];
                av[0]=x0.x; av[1]=x0.y; av[2]=x0.z; av[3]=x0.w;
                av[4]=x1.x; av[5]=x1.y; av[6]=x1.z; av[7]=x1.w;
                av[8]=x2.x; av[9]=x2.y; av[10]=x2.z; av[11]=x2.w;
                av[12]=x3.x; av[13]=x3.y; av[14]=x3.z; av[15]=x3.w;
            } else {
                const short8* p = (const short8*)((const short*)Asrc + (size_t)gr*K + k0 + kc);
                short8 s0 = p[0], s1 = p[1];
                #pragma unroll
                for (int j = 0; j < 8; ++j) {
                    av[j] = bs2f(s0[j]); av[8+j] = bs2f(s1[j]);
                }
            }
            short8 a0, a1;
            #pragma unroll
            for (int j = 0; j < 16; ++j) {
                float v = (av[j] - st.x) * st.y * gs[k0+kc+j] + bs[k0+kc+j];
                if (j < 8) a0[j] = f2bs(v); else a1[j-8] = f2bs(v);
            }
            *(short8*)&As[r*LDK + kc]     = a0;
            *(short8*)&As[r*LDK + kc + 8] = a1;
            int gc = col0 + r;
            const short8* pb = (const short8*)(Wt + (size_t)gc*K + k0 + kc);
            *(short8*)&Bs[r*LDK + kc]     = pb[0];
            *(short8*)&Bs[r*LDK + kc + 8] = pb[1];
        }
        __syncthreads();
        #pragma unroll
        for (int kb = 0; kb < 64; kb += 32) {
            short8 af[4], bfr[4];
            #pragma unroll
            for (int mi = 0; mi < 4; ++mi)
                af[mi] = *(const short8*)&As[(wm*64 + mi*16 + l16)*LDK + kb + quad*8];
            #pragma unroll
            for (int ni = 0; ni < 4; ++ni)
                bfr[ni] = *(const short8*)&Bs[(wn*64 + ni*16 + l16)*LDK + kb + quad*8];
            #pragma unroll
            for (int mi = 0; mi < 4; ++mi)
                #pragma unroll
                for (int ni = 0; ni < 4; ++ni)
                    acc[mi][ni] = __builtin_amdgcn_mfma_f32_16x16x32_bf16(
                        af[mi], bfr[ni], acc[mi][ni], 0, 0, 0);
        }
        __syncthreads();
    }
    #pragma unroll
    for (int mi = 0; mi < 4; ++mi) {
        int rbase = row0 + wm*64 + mi*16 + quad*4;
        #pragma unroll
        for (int ni = 0; ni < 4; ++ni) {
            int c = col0 + wn*64 + ni*16 + l16;
            float bv = bias[c];
            #pragma unroll
            for (int r2 = 0; r2 < 4; ++r2)
                C[(size_t)(rbase + r2)*N + c] = __float2bfloat16(acc[mi][ni][r2] + bv);
        }
    }
}

// ---------- self-attention v4: 1 query/thread, split-K x8, batched-8 softmax ----------
// grid (32, 32), block 256: tid = ql*8 + sub; vectorized K/V staging.
__global__ __launch_bounds__(256) void attn4_kernel(const bf16* __restrict__ qkv,
                                                    float* __restrict__ out){
    int nh = blockIdx.y; int n = nh >> 3, h = nh & 7;
    int tid = threadIdx.x;
    int sub = tid & 7, ql = tid >> 3;
    int q = blockIdx.x*32 + ql;
    bool qok = q < LQ;
    __shared__ float Ks[64][36];
    __shared__ float Vs[64][36];
    const size_t base = (size_t)n * LQ * 768;
    float qreg[32];
    #pragma unroll
    for (int d = 0; d < 32; ++d) qreg[d] = 0.f;
    if (qok) {
        const short8* p = (const short8*)(qkv + base + (size_t)q*768 + h*32);
        #pragma unroll
        for (int c = 0; c < 4; ++c) {
            short8 s = p[c];
            #pragma unroll
            for (int j = 0; j < 8; ++j) qreg[c*8+j] = bs2f(s[j]) * ATT_SCALE;
        }
    }
    float m = -3.0e38f, l = 0.f;
    float4 o8[8];
    #pragma unroll
    for (int w = 0; w < 8; ++w) o8[w] = (float4){0.f,0.f,0.f,0.f};

    int srow = tid >> 2, skc = (tid & 3) * 8;   // staging: row 0..63, col-chunk 0/8/16/24
    for (int j0 = 0; j0 < LQ; j0 += 64) {
        int cnt = min(64, LQ - j0);     // 64 or 40 (multiple of 8)
        if (srow < cnt) {
            size_t rb = base + (size_t)(j0+srow)*768 + h*32 + skc;
            short8 ks = *(const short8*)(qkv + rb + 256);
            short8 vs = *(const short8*)(qkv + rb + 512);
            float4 k0v = { bs2f(ks[0]), bs2f(ks[1]), bs2f(ks[2]), bs2f(ks[3]) };
            float4 k1v = { bs2f(ks[4]), bs2f(ks[5]), bs2f(ks[6]), bs2f(ks[7]) };
            float4 v0v = { bs2f(vs[0]), bs2f(vs[1]), bs2f(vs[2]), bs2f(vs[3]) };
            float4 v1v = { bs2f(vs[4]), bs2f(vs[5]), bs2f(vs[6]), bs2f(vs[7]) };
            *(float4*)&Ks[srow][skc]   = k0v;
            *(float4*)&Ks[srow][skc+4] = k1v;
            *(float4*)&Vs[srow][skc]   = v0v;
            *(float4*)&Vs[srow][skc+4] = v1v;
        }
        __syncthreads();
        int steps = cnt >> 3;           // 8 or 5
        float sca[8];
        #pragma unroll
        for (int t = 0; t < 8; ++t) {
            sca[t] = -3.0e38f;
            if (t < steps) {
                const float4* kr = (const float4*)&Ks[t*8 + sub][0];
                float s = 0.f;
                #pragma unroll
                for (int w = 0; w < 8; ++w) {
                    float4 kv = kr[w];
                    s = fmaf(qreg[4*w],   kv.x, s);
                    s = fmaf(qreg[4*w+1], kv.y, s);
                    s = fmaf(qreg[4*w+2], kv.z, s);
                    s = fmaf(qreg[4*w+3], kv.w, s);
                }
                sca[t] = s;
            }
        }
        float tm = sca[0];
        #pragma unroll
        for (int t = 1; t < 8; ++t) tm = fmaxf(tm, sca[t]);
        float mn = fmaxf(m, tm);
        float c0 = __expf(m - mn);
        float pa[8], sp = 0.f;
        #pragma unroll
        for (int t = 0; t < 8; ++t) { pa[t] = __expf(sca[t] - mn); sp += pa[t]; }
        l = l*c0 + sp;
        m = mn;
        #pragma unroll
        for (int w = 0; w < 8; ++w) {
            float4 o4 = o8[w];
            o4.x *= c0; o4.y *= c0; o4.z *= c0; o4.w *= c0;
            #pragma unroll
            for (int t = 0; t < 8; ++t) {
                float4 vv = *(const float4*)&Vs[t*8 + sub][w*4];
                o4.x = fmaf(pa[t], vv.x, o4.x);
                o4.y = fmaf(pa[t], vv.y, o4.y);
                o4.z = fmaf(pa[t], vv.z, o4.z);
                o4.w = fmaf(pa[t], vv.w, o4.w);
            }
            o8[w] = o4;
        }
        __syncthreads();
    }
    // combine 8 k-slices (8 consecutive lanes per query)
    #pragma unroll
    for (int off = 1; off < 8; off <<= 1) {
        float mo = __shfl_xor(m, off, 64);
        float lo = __shfl_xor(l, off, 64);
        float mn = fmaxf(m, mo);
        float a = __expf(m - mn), bb = __expf(mo - mn);
        l = l*a + lo*bb;
        #pragma unroll
        for (int w = 0; w < 8; ++w) {
            float4 o4 = o8[w];
            float x0 = __shfl_xor(o4.x, off, 64);
            float x1 = __shfl_xor(o4.y, off, 64);
            float x2 = __shfl_xor(o4.z, off, 64);
            float x3 = __shfl_xor(o4.w, off, 64);
            o4.x = o4.x*a + x0*bb;
            o4.y = o4.y*a + x1*bb;
            o4.z = o4.z*a + x2*bb;
            o4.w = o4.w*a + x3*bb;
            o8[w] = o4;
        }
        m = mn;
    }
    if (qok) {
        float inv = 1.f / l;
        float4 sel = o8[0];
        #pragma unroll
        for (int c = 1; c < 8; ++c) if (sub == c) sel = o8[c];
        float4 ov = { sel.x*inv, sel.y*inv, sel.z*inv, sel.w*inv };
        *(float4*)&out[((size_t)n*LQ + q)*256 + h*32 + sub*4] = ov;
    }
}

// ---------- deformable sampling with fused aw-softmax + shuffle broadcasts ----------
__global__ __launch_bounds__(256) void sample2_kernel(
        const bf16* __restrict__ value, const float* __restrict__ offaw,
        const float* __restrict__ cp, float* __restrict__ out){
    int nq = blockIdx.x;
    int n = nq / LQ;
    int d = threadIdx.x & 31, h = threadIdx.x >> 5;
    float cx = cp[nq*2], cy = cp[nq*2+1];
    const float* rowp = offaw + (size_t)nq*480;
    float o0 = rowp[h*40 + d];
    float o1 = (d < 8) ? rowp[h*40 + 32 + d] : 0.f;
    float logit = (d < 20) ? rowp[320 + h*20 + d] : -3.0e38f;
    float mx = logit;
    #pragma unroll
    for (int off = 16; off; off >>= 1) mx = fmaxf(mx, __shfl_xor(mx, off, 32));
    float p = (d < 20) ? __expf(logit - mx) : 0.f;
    float sm = p;
    #pragma unroll
    for (int off = 16; off; off >>= 1) sm += __shfl_xor(sm, off, 32);
    p *= (1.f / sm);

    const int HW[5] = {128,64,32,16,8};
    const int ST[5] = {0,16384,20480,21504,21760};
    float acc = 0.f;
    #pragma unroll
    for (int l = 0; l < 5; ++l) {
        int hw = HW[l];
        float fhw = (float)hw;
        size_t vb = ((size_t)n*LIN + ST[l]) * 256 + h*32 + d;
        #pragma unroll
        for (int pi = 0; pi < 4; ++pi) {
            const int idx = l*4 + pi;
            float w  = __shfl(p, idx, 32);
            float ox = (2*idx < 32)   ? __shfl(o0, 2*idx, 32)   : __shfl(o1, 2*idx-32, 32);
            float oy = (2*idx+1 < 32) ? __shfl(o0, 2*idx+1, 32) : __shfl(o1, 2*idx+1-32, 32);
            float gx = cx*fhw + ox - 0.5f;
            float gy = cy*fhw + oy - 0.5f;
            float x0f = floorf(gx), y0f = floorf(gy);
            float lx = gx - x0f, ly = gy - y0f;
            int x0 = (int)x0f, y0 = (int)y0f;
            float s = 0.f;
            if ((unsigned)y0     < (unsigned)hw && (unsigned)x0     < (unsigned)hw)
                s += (1.f-ly)*(1.f-lx)*__bfloat162float(value[vb + (size_t)(y0*hw + x0)*256]);
            if ((unsigned)y0     < (unsigned)hw && (unsigned)(x0+1) < (unsigned)hw)
                s += (1.f-ly)*lx      *__bfloat162float(value[vb + (size_t)(y0*hw + x0+1)*256]);
            if ((unsigned)(y0+1) < (unsigned)hw && (unsigned)x0     < (unsigned)hw)
                s += ly*(1.f-lx)      *__bfloat162float(value[vb + (size_t)((y0+1)*hw + x0)*256]);
            if ((unsigned)(y0+1) < (unsigned)hw && (unsigned)(x0+1) < (unsigned)hw)
                s += ly*lx            *__bfloat162float(value[vb + (size_t)((y0+1)*hw + x0+1)*256]);
            acc += w * s;
        }
    }
    out[(size_t)nq*256 + h*32 + d] = acc;
}

// ---------- final store ----------
__global__ void final_kernel(const float* __restrict__ in, void* __restrict__ out,
                             int n, const int* __restrict__ flag){
    int f = flag[0];
    int i = blockIdx.x*256 + threadIdx.x;
    if (i >= n) return;
    float v = in[i];
    if (!isfinite(v)) v = 0.f;
    if (f) ((float*)out)[i] = v;
    else   ((bf16*)out)[i] = __float2bfloat16(v);
}

extern "C" void kernel_launch(void* const* d_in, const int* in_sizes, int n_in,
                              void* d_out, int out_size, void* d_ws, size_t ws_size,
                              hipStream_t stream){
    const void* x_raw  = d_in[0];
    const void* src    = d_in[1];
    const void* cp_raw = d_in[2];
    char* ws = (char*)d_ws;
    size_t off = 0;
    auto alloc = [&](size_t bytes){ size_t p = off; off += (bytes + 255) & ~(size_t)255; return p; };
    int*   flag  = (int*)(ws + alloc(256));
    float* xf    = (float*)(ws + alloc((size_t)ROWS_X*DIM*4));
    float* pe    = (float*)(ws + alloc((size_t)ROWS_X*DIM*4));
    float* nbuf  = (float*)(ws + alloc((size_t)ROWS_X*DIM*4));
    float* tmp   = (float*)(ws + alloc((size_t)ROWS_X*DIM*4));
    bf16*  qkv   = (bf16*)(ws + alloc((size_t)ROWS_X*768*2));
    bf16*  ffh   = (bf16*)(ws + alloc((size_t)ROWS_X*MLPD*2));
    float* offaw = (float*)(ws + alloc((size_t)ROWS_X*480*4));
    float2* stats = (float2*)(ws + alloc((size_t)ROWS_SRC*8));
    float* cpf   = (float*)(ws + alloc((size_t)ROWS_X*2*4));
    float* oab   = (float*)(ws + alloc((size_t)2*480*4));
    const int sidx[13] = {5,6,7,8,11,12,13,19,21,22,23,25,27};
    const int ssz[13]  = {512,256,512,512,512,512,512,512,512,512,512,1024,512};
    float* sp[13];
    for (int j = 0; j < 13; ++j) sp[j] = (float*)(ws + alloc((size_t)ssz[j]*4));
    short* qkvT = (short*)(ws + alloc((size_t)2*768*256*2));
    short* outT = (short*)(ws + alloc((size_t)2*256*256*2));
    short* oawT = (short*)(ws + alloc((size_t)2*480*256*2));
    short* valT = (short*)(ws + alloc((size_t)2*256*256*2));
    short* opT  = (short*)(ws + alloc((size_t)2*256*256*2));
    short* ff1T = (short*)(ws + alloc((size_t)2*512*256*2));
    short* ff2T = (short*)(ws + alloc((size_t)2*256*512*2));
    bf16*  val  = (bf16*)(ws + alloc((size_t)ROWS_SRC*DIM*2));
    (void)ws_size; (void)in_sizes; (void)n_in; (void)out_size;

    detect_kernel<<<1, 256, 0, stream>>>(x_raw, flag);
    conv_kernel<<<(ROWS_X*DIM+255)/256, 256, 0, stream>>>(x_raw, xf, ROWS_X*DIM, flag);
    conv_kernel<<<(ROWS_X*2+255)/256, 256, 0, stream>>>(cp_raw, cpf, ROWS_X*2, flag);
    PTab pt;
    for (int j = 0; j < 13; ++j) { pt.src[j] = d_in[sidx[j]]; pt.dst[j] = sp[j]; pt.n[j] = ssz[j]; }
    convs_kernel<<<dim3(4,13), 256, 0, stream>>>(pt, flag);
    catb_kernel<<<dim3(2,2), 256, 0, stream>>>(d_in[15], d_in[17], flag, oab);
    wtrans_kernel<<<dim3(8,24,2), 256, 0, stream>>>(d_in[9],  flag, qkvT, 256, 768, 768, 0);
    wtrans_kernel<<<dim3(8,8,2),  256, 0, stream>>>(d_in[10], flag, outT, 256, 256, 256, 0);
    wtrans_kernel<<<dim3(8,10,2), 256, 0, stream>>>(d_in[14], flag, oawT, 256, 320, 480, 0);
    wtrans_kernel<<<dim3(8,5,2),  256, 0, stream>>>(d_in[16], flag, oawT, 256, 160, 480, 320);
    wtrans_kernel<<<dim3(8,8,2),  256, 0, stream>>>(d_in[18], flag, valT, 256, 256, 256, 0);
    wtrans_kernel<<<dim3(8,8,2),  256, 0, stream>>>(d_in[20], flag, opT,  256, 256, 256, 0);
    wtrans_kernel<<<dim3(8,16,2), 256, 0, stream>>>(d_in[24], flag, ff1T, 256, 512, 512, 0);
    wtrans_kernel<<<dim3(16,8,2), 256, 0, stream>>>(d_in[26], flag, ff2T, 512, 256, 256, 0);

    float* pos_w = sp[0];  float* pos_b = sp[1];
    float* ln1_g = sp[2];  float* ln1_b = sp[3];
    float* out_b = sp[4];
    float* ln2_g = sp[5];  float* ln2_b = sp[6];
    float* val_b = sp[7];  float* op_b  = sp[8];
    float* ln3_g = sp[9];  float* ln3_b = sp[10];
    float* ff_b1 = sp[11]; float* ff_b2 = sp[12];

    pe_kernel<<<ROWS_X, 256, 0, stream>>>(cpf, pos_w, pos_b, pe);
    stats_kernel<<<ROWS_SRC, 256, 0, stream>>>(src, flag, stats);

    int gmx = (ROWS_X + 63) / 64;   // 63
    for (int i = 0; i < 2; ++i) {
        // --- self attention ---
        ln_kernel<<<ROWS_X, 256, 0, stream>>>(xf, pe, nullptr, ln1_g + i*DIM, ln1_b + i*DIM, nbuf);
        mgemm_kernel<<<dim3(gmx,12), 256, 0, stream>>>(
            nbuf, qkvT + (size_t)i*768*256, nullptr, nullptr, qkv, ROWS_X, 256, 768, 0, 0, 1);
        attn4_kernel<<<dim3(32,32), 256, 0, stream>>>(qkv, tmp);
        mgemm_kernel<<<dim3(gmx,4), 256, 0, stream>>>(
            tmp, outT + (size_t)i*256*256, out_b + i*DIM, xf, xf, ROWS_X, 256, 256, 0, 0, 0);
        // --- deformable cross attention ---
        mgemm128_kernel<<<dim3(ROWS_SRC/128, 2), 256, 0, stream>>>(
            src, flag, stats, ln2_g + i*DIM, ln2_b + i*DIM,
            valT + (size_t)i*256*256, val_b + i*DIM, val, 256, 256);
        ln_kernel<<<ROWS_X, 256, 0, stream>>>(xf, nullptr, pe, ln2_g + i*DIM, ln2_b + i*DIM, nbuf);
        mgemm_kernel<<<dim3(gmx,8), 256, 0, stream>>>(
            nbuf, oawT + (size_t)i*480*256, oab + i*480, nullptr, offaw, ROWS_X, 256, 480, 0, 0, 0);
        sample2_kernel<<<ROWS_X, 256, 0, stream>>>(val, offaw, cpf, tmp);
        mgemm_kernel<<<dim3(gmx,4), 256, 0, stream>>>(
            tmp, opT + (size_t)i*256*256, op_b + i*DIM, xf, xf, ROWS_X, 256, 256, 0, 0, 0);
        // --- feedforward ---
        ln_kernel<<<ROWS_X, 256, 0, stream>>>(xf, nullptr, nullptr, ln3_g + i*DIM, ln3_b + i*DIM, nbuf);
        mgemm_kernel<<<dim3(gmx,8), 256, 0, stream>>>(
            nbuf, ff1T + (size_t)i*512*256, ff_b1 + i*MLPD, nullptr, ffh, ROWS_X, 256, 512, 1, 0, 1);
        mgemm_kernel<<<dim3(gmx,4), 256, 0, stream>>>(
            ffh, ff2T + (size_t)i*256*512, ff_b2 + i*DIM, xf, xf, ROWS_X, 512, 256, 0, 2, 0);
    }
    final_kernel<<<(ROWS_X*DIM+255)/256, 256, 0, stream>>>(xf, d_out, ROWS_X*DIM, flag);
}

// Round 8
// 824.636 us; speedup vs baseline: 1.2054x; 1.0487x over previous
//
#include <hip/hip_runtime.h>
#include <hip/hip_bf16.h>
#include <math.h>

#define DIM 256
#define NB 4
#define LQ 1000
#define MLPD 512
#define LIN 21824
#define ROWS_X 4000
#define ROWS_SRC 87296
#define ATT_SCALE 0.17677669529663687f  /* 32^-0.5 */
#define LDK 72   /* padded LDS row (bf16 elems): 144 B, 16B-aligned */

typedef __hip_bfloat16 bf16;
typedef __attribute__((ext_vector_type(8))) short short8;
typedef __attribute__((ext_vector_type(4))) float floatx4;

__device__ __forceinline__ float rdv(const void* p, int f, size_t i){
    if (f) return ((const float*)p)[i];
    unsigned u = ((unsigned)((const unsigned short*)p)[i]) << 16;
    union { unsigned u; float f; } c; c.u = u; return c.f;
}
__device__ __forceinline__ short f2bs(float v){
    bf16 h = __float2bfloat16(v);
    return *reinterpret_cast<short*>(&h);
}
__device__ __forceinline__ float bs2f(short s){
    union { unsigned u; float f; } c; c.u = ((unsigned)(unsigned short)s) << 16; return c.f;
}

// ---------- dtype detect ----------
__global__ void detect_kernel(const void* __restrict__ x, int* __restrict__ flag){
    const unsigned short* u = (const unsigned short*)x;
    int t = threadIdx.x;
    bool hit = false;
    #pragma unroll
    for (int k = 0; k < 4; ++k) {
        unsigned short b = u[(t*4 + k)*2];
        union { unsigned u; float f; } c; c.u = ((unsigned)b) << 16;
        if (!(fabsf(c.f) <= 1000.f)) hit = true;
    }
    unsigned long long m = __ballot(hit);
    __shared__ unsigned long long red[4];
    if ((t & 63) == 0) red[t >> 6] = m;
    __syncthreads();
    if (t == 0) flag[0] = ((red[0]|red[1]|red[2]|red[3]) != 0ULL) ? 1 : 0;
}

__global__ void conv_kernel(const void* __restrict__ in, float* __restrict__ out,
                            int n, const int* __restrict__ flag){
    int f = flag[0];
    int i = blockIdx.x*256 + threadIdx.x;
    if (i < n) out[i] = rdv(in, f, i);
}

// ---------- fused small-param conversions ----------
struct PTab { const void* src[13]; float* dst[13]; int n[13]; };
__global__ void convs_kernel(PTab t, const int* __restrict__ flag){
    int f = flag[0];
    int j = blockIdx.y;
    int i = blockIdx.x*256 + threadIdx.x;
    if (i < t.n[j]) t.dst[j][i] = rdv(t.src[j], f, i);
}

// ---------- concat off_b|aw_b into oab[2][480] ----------
__global__ void catb_kernel(const void* __restrict__ offb, const void* __restrict__ awb,
                            const int* __restrict__ flag, float* __restrict__ oab){
    int f = flag[0];
    int layer = blockIdx.y;
    int idx = blockIdx.x*256 + threadIdx.x;
    if (idx >= 480) return;
    float v = (idx < 320) ? rdv(offb, f, (size_t)layer*320 + idx)
                          : rdv(awb,  f, (size_t)layer*160 + idx - 320);
    oab[layer*480 + idx] = v;
}

// ---------- weight transpose: W[b][K][N] -> Wt[b][ldout][K] bf16 at row offset ----------
__global__ void wtrans_kernel(const void* __restrict__ W, const int* __restrict__ flag,
                              short* __restrict__ Wt, int K, int N, int ldout, int rowoff){
    int f = flag[0];
    int b = blockIdx.z;
    __shared__ float t[32][33];
    int k0 = blockIdx.x*32, n0 = blockIdx.y*32;
    int tx = threadIdx.x & 31, ty = threadIdx.x >> 5;
    size_t base = (size_t)b * K * N;
    for (int i = ty; i < 32; i += 8) {
        int k = k0 + i, n = n0 + tx;
        t[i][tx] = (k < K && n < N) ? rdv(W, f, base + (size_t)k*N + n) : 0.f;
    }
    __syncthreads();
    for (int i = ty; i < 32; i += 8) {
        int n = n0 + i, k = k0 + tx;
        if (n < N && k < K)
            Wt[(size_t)b*ldout*K + (size_t)(rowoff+n)*K + k] = f2bs(t[tx][i]);
    }
}

// ---------- pe ----------
__global__ void pe_kernel(const float* __restrict__ cp, const float* __restrict__ pw,
                          const float* __restrict__ pb, float* __restrict__ pe){
    int row = blockIdx.x, t = threadIdx.x;
    float cx = cp[row*2], cy = cp[row*2+1];
    pe[(size_t)row*DIM + t] = cx*pw[t] + cy*pw[DIM+t] + pb[t];
}

// ---------- per-row stats of src ----------
__global__ void stats_kernel(const void* __restrict__ src, const int* __restrict__ flag,
                             float2* __restrict__ stats){
    int f = flag[0];
    int row = blockIdx.x, t = threadIdx.x;
    float v = rdv(src, f, (size_t)row*DIM + t);
    __shared__ float red[4];
    __shared__ float mean_s;
    float s = v;
    #pragma unroll
    for (int o = 32; o; o >>= 1) s += __shfl_down(s, o, 64);
    int lane = t & 63, wid = t >> 6;
    if (lane == 0) red[wid] = s;
    __syncthreads();
    if (t == 0) mean_s = (red[0]+red[1]+red[2]+red[3]) * (1.f/DIM);
    __syncthreads();
    float xm = v - mean_s;
    float s2 = xm*xm;
    #pragma unroll
    for (int o = 32; o; o >>= 1) s2 += __shfl_down(s2, o, 64);
    if (lane == 0) red[wid] = s2;
    __syncthreads();
    if (t == 0) {
        float var = (red[0]+red[1]+red[2]+red[3]) * (1.f/DIM);
        stats[row] = make_float2(mean_s, rsqrtf(var + 1e-5f));
    }
}

// ---------- LayerNorm: out = LN(in [+pre]) * g + b [+post] ----------
__global__ void ln_kernel(const float* __restrict__ in, const float* __restrict__ pre,
                          const float* __restrict__ post,
                          const float* __restrict__ g, const float* __restrict__ b,
                          float* __restrict__ out){
    int row = blockIdx.x, t = threadIdx.x;
    size_t base = (size_t)row * DIM;
    float v = in[base + t];
    if (pre) v += pre[base + t];
    __shared__ float red[4];
    __shared__ float mean_s, rstd_s;
    float s = v;
    #pragma unroll
    for (int o = 32; o; o >>= 1) s += __shfl_down(s, o, 64);
    int lane = t & 63, wid = t >> 6;
    if (lane == 0) red[wid] = s;
    __syncthreads();
    if (t == 0) mean_s = (red[0]+red[1]+red[2]+red[3]) * (1.f/DIM);
    __syncthreads();
    float xm = v - mean_s;
    float s2 = xm*xm;
    #pragma unroll
    for (int o = 32; o; o >>= 1) s2 += __shfl_down(s2, o, 64);
    if (lane == 0) red[wid] = s2;
    __syncthreads();
    if (t == 0) rstd_s = rsqrtf((red[0]+red[1]+red[2]+red[3]) * (1.f/DIM) + 1e-5f);
    __syncthreads();
    float ov = xm * rstd_s * g[t] + b[t];
    if (post) ov += post[base + t];
    out[base + t] = ov;
}

// ---------- MFMA GEMM 64x64: C = A @ Wt^T (+bias)(gelu?)(+res) ----------
__global__ __launch_bounds__(256) void mgemm_kernel(
    const void* __restrict__ Asrc,
    const short* __restrict__ Wt, const float* __restrict__ bias, const float* res,
    void* Cout, int M, int K, int N, int act, int amode, int cbf){
    __shared__ short As[64*LDK];
    __shared__ short Bs[64*LDK];
    int tid = threadIdx.x;
    int wave = tid >> 6, lane = tid & 63;
    int wm = wave >> 1, wn = wave & 1;
    int quad = lane >> 4, l16 = lane & 15;
    int row0 = blockIdx.x*64, col0 = blockIdx.y*64;
    floatx4 acc[2][2];
    #pragma unroll
    for (int i = 0; i < 2; ++i)
        #pragma unroll
        for (int j = 0; j < 2; ++j)
            acc[i][j] = (floatx4){0.f,0.f,0.f,0.f};

    int r  = tid >> 2;
    int kc = (tid & 3) * 16;
    int gr = row0 + r;
    int gc = col0 + r;
    const short8 z8 = {0,0,0,0,0,0,0,0};

    for (int k0 = 0; k0 < K; k0 += 64) {
        short8 a0 = z8, a1 = z8;
        if (gr < M) {
            if (amode == 2) {
                const short8* p = (const short8*)((const short*)Asrc + (size_t)gr*K + k0 + kc);
                a0 = p[0]; a1 = p[1];
            } else {
                const float4* p = (const float4*)((const float*)Asrc + (size_t)gr*K + k0 + kc);
                float4 x0 = p[0], x1 = p[1], x2 = p[2], x3 = p[3];
                a0[0]=f2bs(x0.x); a0[1]=f2bs(x0.y); a0[2]=f2bs(x0.z); a0[3]=f2bs(x0.w);
                a0[4]=f2bs(x1.x); a0[5]=f2bs(x1.y); a0[6]=f2bs(x1.z); a0[7]=f2bs(x1.w);
                a1[0]=f2bs(x2.x); a1[1]=f2bs(x2.y); a1[2]=f2bs(x2.z); a1[3]=f2bs(x2.w);
                a1[4]=f2bs(x3.x); a1[5]=f2bs(x3.y); a1[6]=f2bs(x3.z); a1[7]=f2bs(x3.w);
            }
        }
        *(short8*)&As[r*LDK + kc]     = a0;
        *(short8*)&As[r*LDK + kc + 8] = a1;
        short8 b0 = z8, b1 = z8;
        if (gc < N) {
            const short8* p = (const short8*)(Wt + (size_t)gc*K + k0 + kc);
            b0 = p[0]; b1 = p[1];
        }
        *(short8*)&Bs[r*LDK + kc]     = b0;
        *(short8*)&Bs[r*LDK + kc + 8] = b1;
        __syncthreads();
        #pragma unroll
        for (int kb = 0; kb < 64; kb += 32) {
            short8 af[2], bfr[2];
            #pragma unroll
            for (int mi = 0; mi < 2; ++mi)
                af[mi] = *(const short8*)&As[(wm*32 + mi*16 + l16)*LDK + kb + quad*8];
            #pragma unroll
            for (int ni = 0; ni < 2; ++ni)
                bfr[ni] = *(const short8*)&Bs[(wn*32 + ni*16 + l16)*LDK + kb + quad*8];
            #pragma unroll
            for (int mi = 0; mi < 2; ++mi)
                #pragma unroll
                for (int ni = 0; ni < 2; ++ni)
                    acc[mi][ni] = __builtin_amdgcn_mfma_f32_16x16x32_bf16(
                        af[mi], bfr[ni], acc[mi][ni], 0, 0, 0);
        }
        __syncthreads();
    }
    #pragma unroll
    for (int mi = 0; mi < 2; ++mi) {
        int rbase = row0 + wm*32 + mi*16 + quad*4;
        #pragma unroll
        for (int ni = 0; ni < 2; ++ni) {
            int c = col0 + wn*32 + ni*16 + l16;
            if (c >= N) continue;
            #pragma unroll
            for (int r2 = 0; r2 < 4; ++r2) {
                int rr = rbase + r2;
                if (rr >= M) continue;
                float v = acc[mi][ni][r2];
                if (bias) v += bias[c];
                if (act) v = 0.5f*v*(1.f + tanhf(0.7978845608028654f*(v + 0.044715f*v*v*v)));
                if (res) v += res[(size_t)rr*N + c];
                if (cbf) ((bf16*)Cout)[(size_t)rr*N + c] = __float2bfloat16(v);
                else     ((float*)Cout)[(size_t)rr*N + c] = v;
            }
        }
    }
}

// ---------- MFMA GEMM 128x128 with fused LN on A (value GEMM) ----------
__global__ __launch_bounds__(256) void mgemm128_kernel(
    const void* __restrict__ Asrc, const int* __restrict__ flag,
    const float2* __restrict__ stats, const float* __restrict__ g, const float* __restrict__ bvec,
    const short* __restrict__ Wt, const float* __restrict__ bias,
    bf16* __restrict__ C, int K, int N){
    __shared__ short As[128*LDK];
    __shared__ short Bs[128*LDK];
    __shared__ float gs[256], bs[256];
    int tid = threadIdx.x;
    int f = flag[0];
    int wave = tid >> 6, lane = tid & 63;
    int wm = wave >> 1, wn = wave & 1;
    int quad = lane >> 4, l16 = lane & 15;
    int row0 = blockIdx.x*128, col0 = blockIdx.y*128;
    if (tid < K) { gs[tid] = g[tid]; bs[tid] = bvec[tid]; }
    floatx4 acc[4][4];
    #pragma unroll
    for (int i = 0; i < 4; ++i)
        #pragma unroll
        for (int j = 0; j < 4; ++j)
            acc[i][j] = (floatx4){0.f,0.f,0.f,0.f};
    __syncthreads();

    for (int k0 = 0; k0 < K; k0 += 64) {
        #pragma unroll
        for (int i = 0; i < 2; ++i) {
            int idx = tid + i*256;
            int r = idx >> 2;
            int kc = (idx & 3) * 16;
            int gr = row0 + r;
            float2 st = stats[gr];
            float av[16];
            if (f) {
                const float4* p = (const float4*)((const float*)Asrc + (size_t)gr*K + k0 + kc);
                float4 x0 = p[0], x1 = p[1], x2 = p[2], x3 = p[3];
                av[0]=x0.x; av[1]=x0.y; av[2]=x0.z; av[3]=x0.w;
                av[4]=x1.x; av[5]=x1.y; av[6]=x1.z; av[7]=x1.w;
                av[8]=x2.x; av[9]=x2.y; av[10]=x2.z; av[11]=x2.w;
                av[12]=x3.x; av[13]=x3.y; av[14]=x3.z; av[15]=x3.w;
            } else {
                const short8* p = (const short8*)((const short*)Asrc + (size_t)gr*K + k0 + kc);
                short8 s0 = p[0], s1 = p[1];
                #pragma unroll
                for (int j = 0; j < 8; ++j) {
                    av[j] = bs2f(s0[j]); av[8+j] = bs2f(s1[j]);
                }
            }
            short8 a0, a1;
            #pragma unroll
            for (int j = 0; j < 16; ++j) {
                float v = (av[j] - st.x) * st.y * gs[k0+kc+j] + bs[k0+kc+j];
                if (j < 8) a0[j] = f2bs(v); else a1[j-8] = f2bs(v);
            }
            *(short8*)&As[r*LDK + kc]     = a0;
            *(short8*)&As[r*LDK + kc + 8] = a1;
            int gc = col0 + r;
            const short8* pb = (const short8*)(Wt + (size_t)gc*K + k0 + kc);
            *(short8*)&Bs[r*LDK + kc]     = pb[0];
            *(short8*)&Bs[r*LDK + kc + 8] = pb[1];
        }
        __syncthreads();
        #pragma unroll
        for (int kb = 0; kb < 64; kb += 32) {
            short8 af[4], bfr[4];
            #pragma unroll
            for (int mi = 0; mi < 4; ++mi)
                af[mi] = *(const short8*)&As[(wm*64 + mi*16 + l16)*LDK + kb + quad*8];
            #pragma unroll
            for (int ni = 0; ni < 4; ++ni)
                bfr[ni] = *(const short8*)&Bs[(wn*64 + ni*16 + l16)*LDK + kb + quad*8];
            #pragma unroll
            for (int mi = 0; mi < 4; ++mi)
                #pragma unroll
                for (int ni = 0; ni < 4; ++ni)
                    acc[mi][ni] = __builtin_amdgcn_mfma_f32_16x16x32_bf16(
                        af[mi], bfr[ni], acc[mi][ni], 0, 0, 0);
        }
        __syncthreads();
    }
    #pragma unroll
    for (int mi = 0; mi < 4; ++mi) {
        int rbase = row0 + wm*64 + mi*16 + quad*4;
        #pragma unroll
        for (int ni = 0; ni < 4; ++ni) {
            int c = col0 + wn*64 + ni*16 + l16;
            float bv = bias[c];
            #pragma unroll
            for (int r2 = 0; r2 < 4; ++r2)
                C[(size_t)(rbase + r2)*N + c] = __float2bfloat16(acc[mi][ni][r2] + bv);
        }
    }
}

// ---------- attention stage 1: S = (Q*scale) @ K^T, bf16, cols padded to 1024 ----------
// grid (16 qtile, 16 ktile, 16 hh); S[hh][1000][1024]
__global__ __launch_bounds__(256) void sattn_kernel(const short* __restrict__ qkv,
                                                    short* __restrict__ S, int half){
    int hh = blockIdx.z;
    int nh = half*16 + hh;
    int n = nh >> 3, h = nh & 7;
    int q0 = blockIdx.x * 64, k0 = blockIdx.y * 64;
    __shared__ short As[64*40];
    __shared__ short Bs[64*40];
    int tid = threadIdx.x;
    int r = tid >> 2, c = (tid & 3) * 8;
    const short8 z8 = {0,0,0,0,0,0,0,0};
    {
        int gq = q0 + r;
        short8 a = z8;
        if (gq < LQ) {
            short8 s = *(const short8*)(qkv + ((size_t)(n*LQ+gq))*768 + h*32 + c);
            #pragma unroll
            for (int j = 0; j < 8; ++j) a[j] = f2bs(bs2f(s[j]) * ATT_SCALE);
        }
        *(short8*)&As[r*40 + c] = a;
        int gk = k0 + r;
        short8 b = z8;
        if (gk < LQ)
            b = *(const short8*)(qkv + ((size_t)(n*LQ+gk))*768 + 256 + h*32 + c);
        *(short8*)&Bs[r*40 + c] = b;
    }
    __syncthreads();
    int wave = tid >> 6, lane = tid & 63;
    int wm = wave >> 1, wn = wave & 1;
    int quad = lane >> 4, l16 = lane & 15;
    floatx4 acc[2][2];
    #pragma unroll
    for (int mi = 0; mi < 2; ++mi) {
        short8 af = *(const short8*)&As[(wm*32 + mi*16 + l16)*40 + quad*8];
        #pragma unroll
        for (int ni = 0; ni < 2; ++ni) {
            short8 bfr = *(const short8*)&Bs[(wn*32 + ni*16 + l16)*40 + quad*8];
            acc[mi][ni] = __builtin_amdgcn_mfma_f32_16x16x32_bf16(
                af, bfr, (floatx4){0.f,0.f,0.f,0.f}, 0, 0, 0);
        }
    }
    #pragma unroll
    for (int mi = 0; mi < 2; ++mi) {
        int rbase = q0 + wm*32 + mi*16 + quad*4;
        #pragma unroll
        for (int ni = 0; ni < 2; ++ni) {
            int col = k0 + wn*32 + ni*16 + l16;
            #pragma unroll
            for (int r2 = 0; r2 < 4; ++r2) {
                int row = rbase + r2;
                if (row < LQ)
                    S[((size_t)hh*LQ + row)*1024 + col] = f2bs(acc[mi][ni][r2]);
            }
        }
    }
}

// ---------- attention stage 2: row softmax over 1000 cols, in place ----------
// grid (1000, 16), block 256 (threads 0..249 hold 4 cols each)
__global__ __launch_bounds__(256) void asoftmax_kernel(short* __restrict__ S){
    int q = blockIdx.x, hh = blockIdx.y;
    short* row = S + ((size_t)hh*LQ + q)*1024;
    int t = threadIdx.x;
    bool act = t < 250;
    float v[4];
    if (act) {
        ushort4 u = *(const ushort4*)((const unsigned short*)row + t*4);
        v[0]=bs2f((short)u.x); v[1]=bs2f((short)u.y); v[2]=bs2f((short)u.z); v[3]=bs2f((short)u.w);
    } else { v[0]=v[1]=v[2]=v[3] = -3.0e38f; }
    float m = fmaxf(fmaxf(v[0],v[1]), fmaxf(v[2],v[3]));
    __shared__ float redm[4], reds[4];
    #pragma unroll
    for (int o = 32; o; o >>= 1) m = fmaxf(m, __shfl_xor(m, o, 64));
    int lane = t & 63, wid = t >> 6;
    if (lane == 0) redm[wid] = m;
    __syncthreads();
    float gm = fmaxf(fmaxf(redm[0],redm[1]), fmaxf(redm[2],redm[3]));
    float p0=0.f,p1=0.f,p2=0.f,p3=0.f;
    if (act) {
        p0 = __expf(v[0]-gm); p1 = __expf(v[1]-gm);
        p2 = __expf(v[2]-gm); p3 = __expf(v[3]-gm);
    }
    float s = p0+p1+p2+p3;
    #pragma unroll
    for (int o = 32; o; o >>= 1) s += __shfl_xor(s, o, 64);
    if (lane == 0) reds[wid] = s;
    __syncthreads();
    float inv = 1.f / (reds[0]+reds[1]+reds[2]+reds[3]);
    if (act) {
        ushort4 u;
        u.x = (unsigned short)f2bs(p0*inv); u.y = (unsigned short)f2bs(p1*inv);
        u.z = (unsigned short)f2bs(p2*inv); u.w = (unsigned short)f2bs(p3*inv);
        *(ushort4*)((unsigned short*)row + t*4) = u;
    }
}

// ---------- attention stage 3: O = P @ V ----------
// grid (16 qtile, 16 hh), block 256 (4 waves, 16 q-rows each)
__global__ __launch_bounds__(256) void pv_kernel(const short* __restrict__ S,
                                                 const short* __restrict__ qkv,
                                                 float* __restrict__ out, int half){
    int hh = blockIdx.y;
    int nh = half*16 + hh;
    int n = nh >> 3, h = nh & 7;
    int q0 = blockIdx.x * 64;
    __shared__ short Ps[64*72];
    __shared__ short VsT[32*72];
    int tid = threadIdx.x;
    int wave = tid >> 6, lane = tid & 63;
    int quad = lane >> 4, l16 = lane & 15;
    int r = tid >> 2;
    int cp = (tid & 3) * 16;
    int cv = (tid & 3) * 8;
    const short8 z8 = {0,0,0,0,0,0,0,0};
    floatx4 acc[2];
    acc[0] = (floatx4){0.f,0.f,0.f,0.f};
    acc[1] = (floatx4){0.f,0.f,0.f,0.f};

    for (int k0 = 0; k0 < 1024; k0 += 64) {
        short8 p0 = z8, p1 = z8;
        int gq = q0 + r;
        if (gq < LQ) {
            const short* sp = S + ((size_t)hh*LQ + gq)*1024 + k0 + cp;
            p0 = *(const short8*)sp;
            p1 = *(const short8*)(sp + 8);
        }
        *(short8*)&Ps[r*72 + cp]     = p0;
        *(short8*)&Ps[r*72 + cp + 8] = p1;
        int gk = k0 + r;
        short8 vv = z8;
        if (gk < LQ)
            vv = *(const short8*)(qkv + ((size_t)(n*LQ+gk))*768 + 512 + h*32 + cv);
        #pragma unroll
        for (int j = 0; j < 8; ++j) VsT[(cv+j)*72 + r] = vv[j];
        __syncthreads();
        #pragma unroll
        for (int kb = 0; kb < 64; kb += 32) {
            short8 af = *(const short8*)&Ps[(wave*16 + l16)*72 + kb + quad*8];
            #pragma unroll
            for (int ni = 0; ni < 2; ++ni) {
                short8 bfr = *(const short8*)&VsT[(ni*16 + l16)*72 + kb + quad*8];
                acc[ni] = __builtin_amdgcn_mfma_f32_16x16x32_bf16(af, bfr, acc[ni], 0, 0, 0);
            }
        }
        __syncthreads();
    }
    #pragma unroll
    for (int ni = 0; ni < 2; ++ni)
        #pragma unroll
        for (int r2 = 0; r2 < 4; ++r2) {
            int row = q0 + wave*16 + quad*4 + r2;
            if (row < LQ)
                out[((size_t)(n*LQ+row))*256 + h*32 + ni*16 + l16] = acc[ni][r2];
        }
}

// ---------- deformable sampling with fused aw-softmax + shuffle broadcasts ----------
__global__ __launch_bounds__(256) void sample2_kernel(
        const bf16* __restrict__ value, const float* __restrict__ offaw,
        const float* __restrict__ cp, float* __restrict__ out){
    int nq = blockIdx.x;
    int n = nq / LQ;
    int d = threadIdx.x & 31, h = threadIdx.x >> 5;
    float cx = cp[nq*2], cy = cp[nq*2+1];
    const float* rowp = offaw + (size_t)nq*480;
    float o0 = rowp[h*40 + d];
    float o1 = (d < 8) ? rowp[h*40 + 32 + d] : 0.f;
    float logit = (d < 20) ? rowp[320 + h*20 + d] : -3.0e38f;
    float mx = logit;
    #pragma unroll
    for (int off = 16; off; off >>= 1) mx = fmaxf(mx, __shfl_xor(mx, off, 32));
    float p = (d < 20) ? __expf(logit - mx) : 0.f;
    float sm = p;
    #pragma unroll
    for (int off = 16; off; off >>= 1) sm += __shfl_xor(sm, off, 32);
    p *= (1.f / sm);

    const int HW[5] = {128,64,32,16,8};
    const int ST[5] = {0,16384,20480,21504,21760};
    float acc = 0.f;
    #pragma unroll
    for (int l = 0; l < 5; ++l) {
        int hw = HW[l];
        float fhw = (float)hw;
        size_t vb = ((size_t)n*LIN + ST[l]) * 256 + h*32 + d;
        #pragma unroll
        for (int pi = 0; pi < 4; ++pi) {
            const int idx = l*4 + pi;
            float w  = __shfl(p, idx, 32);
            float ox = (2*idx < 32)   ? __shfl(o0, 2*idx, 32)   : __shfl(o1, 2*idx-32, 32);
            float oy = (2*idx+1 < 32) ? __shfl(o0, 2*idx+1, 32) : __shfl(o1, 2*idx+1-32, 32);
            float gx = cx*fhw + ox - 0.5f;
            float gy = cy*fhw + oy - 0.5f;
            float x0f = floorf(gx), y0f = floorf(gy);
            float lx = gx - x0f, ly = gy - y0f;
            int x0 = (int)x0f, y0 = (int)y0f;
            float s = 0.f;
            if ((unsigned)y0     < (unsigned)hw && (unsigned)x0     < (unsigned)hw)
                s += (1.f-ly)*(1.f-lx)*__bfloat162float(value[vb + (size_t)(y0*hw + x0)*256]);
            if ((unsigned)y0     < (unsigned)hw && (unsigned)(x0+1) < (unsigned)hw)
                s += (1.f-ly)*lx      *__bfloat162float(value[vb + (size_t)(y0*hw + x0+1)*256]);
            if ((unsigned)(y0+1) < (unsigned)hw && (unsigned)x0     < (unsigned)hw)
                s += ly*(1.f-lx)      *__bfloat162float(value[vb + (size_t)((y0+1)*hw + x0)*256]);
            if ((unsigned)(y0+1) < (unsigned)hw && (unsigned)(x0+1) < (unsigned)hw)
                s += ly*lx            *__bfloat162float(value[vb + (size_t)((y0+1)*hw + x0+1)*256]);
            acc += w * s;
        }
    }
    out[(size_t)nq*256 + h*32 + d] = acc;
}

// ---------- final store ----------
__global__ void final_kernel(const float* __restrict__ in, void* __restrict__ out,
                             int n, const int* __restrict__ flag){
    int f = flag[0];
    int i = blockIdx.x*256 + threadIdx.x;
    if (i >= n) return;
    float v = in[i];
    if (!isfinite(v)) v = 0.f;
    if (f) ((float*)out)[i] = v;
    else   ((bf16*)out)[i] = __float2bfloat16(v);
}

extern "C" void kernel_launch(void* const* d_in, const int* in_sizes, int n_in,
                              void* d_out, int out_size, void* d_ws, size_t ws_size,
                              hipStream_t stream){
    const void* x_raw  = d_in[0];
    const void* src    = d_in[1];
    const void* cp_raw = d_in[2];
    char* ws = (char*)d_ws;
    size_t off = 0;
    auto alloc = [&](size_t bytes){ size_t p = off; off += (bytes + 255) & ~(size_t)255; return p; };
    int*   flag  = (int*)(ws + alloc(256));
    float* xf    = (float*)(ws + alloc((size_t)ROWS_X*DIM*4));
    float* pe    = (float*)(ws + alloc((size_t)ROWS_X*DIM*4));
    float* nbuf  = (float*)(ws + alloc((size_t)ROWS_X*DIM*4));
    float* tmp   = (float*)(ws + alloc((size_t)ROWS_X*DIM*4));
    bf16*  qkv   = (bf16*)(ws + alloc((size_t)ROWS_X*768*2));
    bf16*  ffh   = (bf16*)(ws + alloc((size_t)ROWS_X*MLPD*2));
    float* offaw = (float*)(ws + alloc((size_t)ROWS_X*480*4));
    float2* stats = (float2*)(ws + alloc((size_t)ROWS_SRC*8));
    float* cpf   = (float*)(ws + alloc((size_t)ROWS_X*2*4));
    float* oab   = (float*)(ws + alloc((size_t)2*480*4));
    const int sidx[13] = {5,6,7,8,11,12,13,19,21,22,23,25,27};
    const int ssz[13]  = {512,256,512,512,512,512,512,512,512,512,512,1024,512};
    float* sp[13];
    for (int j = 0; j < 13; ++j) sp[j] = (float*)(ws + alloc((size_t)ssz[j]*4));
    short* qkvT = (short*)(ws + alloc((size_t)2*768*256*2));
    short* outT = (short*)(ws + alloc((size_t)2*256*256*2));
    short* oawT = (short*)(ws + alloc((size_t)2*480*256*2));
    short* valT = (short*)(ws + alloc((size_t)2*256*256*2));
    short* opT  = (short*)(ws + alloc((size_t)2*256*256*2));
    short* ff1T = (short*)(ws + alloc((size_t)2*512*256*2));
    short* ff2T = (short*)(ws + alloc((size_t)2*256*512*2));
    bf16*  val  = (bf16*)(ws + alloc((size_t)ROWS_SRC*DIM*2));
    // S (16 nh x 1000 x 1024 bf16 = 31.25 MB) aliases val (44.7 MB):
    // lifetimes are disjoint (S: attention phase; val: mgemm128->sample2 phase).
    short* Sbuf = (short*)val;
    (void)ws_size; (void)in_sizes; (void)n_in; (void)out_size;

    detect_kernel<<<1, 256, 0, stream>>>(x_raw, flag);
    conv_kernel<<<(ROWS_X*DIM+255)/256, 256, 0, stream>>>(x_raw, xf, ROWS_X*DIM, flag);
    conv_kernel<<<(ROWS_X*2+255)/256, 256, 0, stream>>>(cp_raw, cpf, ROWS_X*2, flag);
    PTab pt;
    for (int j = 0; j < 13; ++j) { pt.src[j] = d_in[sidx[j]]; pt.dst[j] = sp[j]; pt.n[j] = ssz[j]; }
    convs_kernel<<<dim3(4,13), 256, 0, stream>>>(pt, flag);
    catb_kernel<<<dim3(2,2), 256, 0, stream>>>(d_in[15], d_in[17], flag, oab);
    wtrans_kernel<<<dim3(8,24,2), 256, 0, stream>>>(d_in[9],  flag, qkvT, 256, 768, 768, 0);
    wtrans_kernel<<<dim3(8,8,2),  256, 0, stream>>>(d_in[10], flag, outT, 256, 256, 256, 0);
    wtrans_kernel<<<dim3(8,10,2), 256, 0, stream>>>(d_in[14], flag, oawT, 256, 320, 480, 0);
    wtrans_kernel<<<dim3(8,5,2),  256, 0, stream>>>(d_in[16], flag, oawT, 256, 160, 480, 320);
    wtrans_kernel<<<dim3(8,8,2),  256, 0, stream>>>(d_in[18], flag, valT, 256, 256, 256, 0);
    wtrans_kernel<<<dim3(8,8,2),  256, 0, stream>>>(d_in[20], flag, opT,  256, 256, 256, 0);
    wtrans_kernel<<<dim3(8,16,2), 256, 0, stream>>>(d_in[24], flag, ff1T, 256, 512, 512, 0);
    wtrans_kernel<<<dim3(16,8,2), 256, 0, stream>>>(d_in[26], flag, ff2T, 512, 256, 256, 0);

    float* pos_w = sp[0];  float* pos_b = sp[1];
    float* ln1_g = sp[2];  float* ln1_b = sp[3];
    float* out_b = sp[4];
    float* ln2_g = sp[5];  float* ln2_b = sp[6];
    float* val_b = sp[7];  float* op_b  = sp[8];
    float* ln3_g = sp[9];  float* ln3_b = sp[10];
    float* ff_b1 = sp[11]; float* ff_b2 = sp[12];

    pe_kernel<<<ROWS_X, 256, 0, stream>>>(cpf, pos_w, pos_b, pe);
    stats_kernel<<<ROWS_SRC, 256, 0, stream>>>(src, flag, stats);

    int gmx = (ROWS_X + 63) / 64;   // 63
    for (int i = 0; i < 2; ++i) {
        // --- self attention (MFMA, materialized S, 2 halves of 16 nh) ---
        ln_kernel<<<ROWS_X, 256, 0, stream>>>(xf, pe, nullptr, ln1_g + i*DIM, ln1_b + i*DIM, nbuf);
        mgemm_kernel<<<dim3(gmx,12), 256, 0, stream>>>(
            nbuf, qkvT + (size_t)i*768*256, nullptr, nullptr, qkv, ROWS_X, 256, 768, 0, 0, 1);
        for (int half = 0; half < 2; ++half) {
            sattn_kernel<<<dim3(16,16,16), 256, 0, stream>>>((const short*)qkv, Sbuf, half);
            asoftmax_kernel<<<dim3(1000,16), 256, 0, stream>>>(Sbuf);
            pv_kernel<<<dim3(16,16), 256, 0, stream>>>(Sbuf, (const short*)qkv, tmp, half);
        }
        mgemm_kernel<<<dim3(gmx,4), 256, 0, stream>>>(
            tmp, outT + (size_t)i*256*256, out_b + i*DIM, xf, xf, ROWS_X, 256, 256, 0, 0, 0);
        // --- deformable cross attention ---
        mgemm128_kernel<<<dim3(ROWS_SRC/128, 2), 256, 0, stream>>>(
            src, flag, stats, ln2_g + i*DIM, ln2_b + i*DIM,
            valT + (size_t)i*256*256, val_b + i*DIM, val, 256, 256);
        ln_kernel<<<ROWS_X, 256, 0, stream>>>(xf, nullptr, pe, ln2_g + i*DIM, ln2_b + i*DIM, nbuf);
        mgemm_kernel<<<dim3(gmx,8), 256, 0, stream>>>(
            nbuf, oawT + (size_t)i*480*256, oab + i*480, nullptr, offaw, ROWS_X, 256, 480, 0, 0, 0);
        sample2_kernel<<<ROWS_X, 256, 0, stream>>>(val, offaw, cpf, tmp);
        mgemm_kernel<<<dim3(gmx,4), 256, 0, stream>>>(
            tmp, opT + (size_t)i*256*256, op_b + i*DIM, xf, xf, ROWS_X, 256, 256, 0, 0, 0);
        // --- feedforward ---
        ln_kernel<<<ROWS_X, 256, 0, stream>>>(xf, nullptr, nullptr, ln3_g + i*DIM, ln3_b + i*DIM, nbuf);
        mgemm_kernel<<<dim3(gmx,8), 256, 0, stream>>>(
            nbuf, ff1T + (size_t)i*512*256, ff_b1 + i*MLPD, nullptr, ffh, ROWS_X, 256, 512, 1, 0, 1);
        mgemm_kernel<<<dim3(gmx,4), 256, 0, stream>>>(
            ffh, ff2T + (size_t)i*256*512, ff_b2 + i*DIM, xf, xf, ROWS_X, 512, 256, 0, 2, 0);
    }
    final_kernel<<<(ROWS_X*DIM+255)/256, 256, 0, stream>>>(xf, d_out, ROWS_X*DIM, flag);
}

// Round 9
// 767.627 us; speedup vs baseline: 1.2950x; 1.0743x over previous
//
#include <hip/hip_runtime.h>
#include <hip/hip_bf16.h>
#include <math.h>

#define DIM 256
#define NB 4
#define LQ 1000
#define MLPD 512
#define LIN 21824
#define ROWS_X 4000
#define ROWS_SRC 87296
#define ATT_SCALE 0.17677669529663687f  /* 32^-0.5 */
#define LDK 72   /* padded LDS row (bf16 elems): 144 B, 16B-aligned */

typedef __hip_bfloat16 bf16;
typedef __attribute__((ext_vector_type(8))) short short8;
typedef __attribute__((ext_vector_type(4))) float floatx4;

__device__ __forceinline__ float rdv(const void* p, int f, size_t i){
    if (f) return ((const float*)p)[i];
    unsigned u = ((unsigned)((const unsigned short*)p)[i]) << 16;
    union { unsigned u; float f; } c; c.u = u; return c.f;
}
__device__ __forceinline__ short f2bs(float v){
    bf16 h = __float2bfloat16(v);
    return *reinterpret_cast<short*>(&h);
}
__device__ __forceinline__ float bs2f(short s){
    union { unsigned u; float f; } c; c.u = ((unsigned)(unsigned short)s) << 16; return c.f;
}

// ---------- dtype detect ----------
__global__ void detect_kernel(const void* __restrict__ x, int* __restrict__ flag){
    const unsigned short* u = (const unsigned short*)x;
    int t = threadIdx.x;
    bool hit = false;
    #pragma unroll
    for (int k = 0; k < 4; ++k) {
        unsigned short b = u[(t*4 + k)*2];
        union { unsigned u; float f; } c; c.u = ((unsigned)b) << 16;
        if (!(fabsf(c.f) <= 1000.f)) hit = true;
    }
    unsigned long long m = __ballot(hit);
    __shared__ unsigned long long red[4];
    if ((t & 63) == 0) red[t >> 6] = m;
    __syncthreads();
    if (t == 0) flag[0] = ((red[0]|red[1]|red[2]|red[3]) != 0ULL) ? 1 : 0;
}

__global__ void conv_kernel(const void* __restrict__ in, float* __restrict__ out,
                            int n, const int* __restrict__ flag){
    int f = flag[0];
    int i = blockIdx.x*256 + threadIdx.x;
    if (i < n) out[i] = rdv(in, f, i);
}

// ---------- fused small-param conversions ----------
struct PTab { const void* src[13]; float* dst[13]; int n[13]; };
__global__ void convs_kernel(PTab t, const int* __restrict__ flag){
    int f = flag[0];
    int j = blockIdx.y;
    int i = blockIdx.x*256 + threadIdx.x;
    if (i < t.n[j]) t.dst[j][i] = rdv(t.src[j], f, i);
}

// ---------- concat off_b|aw_b into oab[2][480] ----------
__global__ void catb_kernel(const void* __restrict__ offb, const void* __restrict__ awb,
                            const int* __restrict__ flag, float* __restrict__ oab){
    int f = flag[0];
    int layer = blockIdx.y;
    int idx = blockIdx.x*256 + threadIdx.x;
    if (idx >= 480) return;
    float v = (idx < 320) ? rdv(offb, f, (size_t)layer*320 + idx)
                          : rdv(awb,  f, (size_t)layer*160 + idx - 320);
    oab[layer*480 + idx] = v;
}

// ---------- weight transpose: W[b][K][N] -> Wt[b][ldout][K] bf16 at row offset ----------
__global__ void wtrans_kernel(const void* __restrict__ W, const int* __restrict__ flag,
                              short* __restrict__ Wt, int K, int N, int ldout, int rowoff){
    int f = flag[0];
    int b = blockIdx.z;
    __shared__ float t[32][33];
    int k0 = blockIdx.x*32, n0 = blockIdx.y*32;
    int tx = threadIdx.x & 31, ty = threadIdx.x >> 5;
    size_t base = (size_t)b * K * N;
    for (int i = ty; i < 32; i += 8) {
        int k = k0 + i, n = n0 + tx;
        t[i][tx] = (k < K && n < N) ? rdv(W, f, base + (size_t)k*N + n) : 0.f;
    }
    __syncthreads();
    for (int i = ty; i < 32; i += 8) {
        int n = n0 + i, k = k0 + tx;
        if (n < N && k < K)
            Wt[(size_t)b*ldout*K + (size_t)(rowoff+n)*K + k] = f2bs(t[tx][i]);
    }
}

// ---------- pe ----------
__global__ void pe_kernel(const float* __restrict__ cp, const float* __restrict__ pw,
                          const float* __restrict__ pb, float* __restrict__ pe){
    int row = blockIdx.x, t = threadIdx.x;
    float cx = cp[row*2], cy = cp[row*2+1];
    pe[(size_t)row*DIM + t] = cx*pw[t] + cy*pw[DIM+t] + pb[t];
}

// ---------- per-row stats of src: one wave per row, shuffle-only ----------
__global__ __launch_bounds__(256) void stats2_kernel(const void* __restrict__ src,
                                                     const int* __restrict__ flag,
                                                     float2* __restrict__ stats){
    int f = flag[0];
    int wave = threadIdx.x >> 6, lane = threadIdx.x & 63;
    int row = blockIdx.x*4 + wave;
    float v0, v1, v2, v3;
    if (f) {
        float4 x = *(const float4*)((const float*)src + (size_t)row*DIM + lane*4);
        v0 = x.x; v1 = x.y; v2 = x.z; v3 = x.w;
    } else {
        ushort4 u = *(const ushort4*)((const unsigned short*)src + (size_t)row*DIM + lane*4);
        v0 = bs2f((short)u.x); v1 = bs2f((short)u.y);
        v2 = bs2f((short)u.z); v3 = bs2f((short)u.w);
    }
    float s  = v0 + v1 + v2 + v3;
    float s2 = v0*v0 + v1*v1 + v2*v2 + v3*v3;
    #pragma unroll
    for (int o = 32; o; o >>= 1) {
        s  += __shfl_xor(s,  o, 64);
        s2 += __shfl_xor(s2, o, 64);
    }
    if (lane == 0) {
        float mean = s * (1.f/DIM);
        float var  = s2 * (1.f/DIM) - mean*mean;
        stats[row] = make_float2(mean, rsqrtf(var + 1e-5f));
    }
}

// ---------- LayerNorm: out = LN(in [+pre]) * g + b [+post] ----------
__global__ void ln_kernel(const float* __restrict__ in, const float* __restrict__ pre,
                          const float* __restrict__ post,
                          const float* __restrict__ g, const float* __restrict__ b,
                          float* __restrict__ out){
    int row = blockIdx.x, t = threadIdx.x;
    size_t base = (size_t)row * DIM;
    float v = in[base + t];
    if (pre) v += pre[base + t];
    __shared__ float red[4];
    __shared__ float mean_s, rstd_s;
    float s = v;
    #pragma unroll
    for (int o = 32; o; o >>= 1) s += __shfl_down(s, o, 64);
    int lane = t & 63, wid = t >> 6;
    if (lane == 0) red[wid] = s;
    __syncthreads();
    if (t == 0) mean_s = (red[0]+red[1]+red[2]+red[3]) * (1.f/DIM);
    __syncthreads();
    float xm = v - mean_s;
    float s2 = xm*xm;
    #pragma unroll
    for (int o = 32; o; o >>= 1) s2 += __shfl_down(s2, o, 64);
    if (lane == 0) red[wid] = s2;
    __syncthreads();
    if (t == 0) rstd_s = rsqrtf((red[0]+red[1]+red[2]+red[3]) * (1.f/DIM) + 1e-5f);
    __syncthreads();
    float ov = xm * rstd_s * g[t] + b[t];
    if (post) ov += post[base + t];
    out[base + t] = ov;
}

// ---------- MFMA GEMM 64x64: C = A @ Wt^T (+bias)(gelu?)(+res) ----------
__global__ __launch_bounds__(256) void mgemm_kernel(
    const void* __restrict__ Asrc,
    const short* __restrict__ Wt, const float* __restrict__ bias, const float* res,
    void* Cout, int M, int K, int N, int act, int amode, int cbf){
    __shared__ short As[64*LDK];
    __shared__ short Bs[64*LDK];
    int tid = threadIdx.x;
    int wave = tid >> 6, lane = tid & 63;
    int wm = wave >> 1, wn = wave & 1;
    int quad = lane >> 4, l16 = lane & 15;
    int row0 = blockIdx.x*64, col0 = blockIdx.y*64;
    floatx4 acc[2][2];
    #pragma unroll
    for (int i = 0; i < 2; ++i)
        #pragma unroll
        for (int j = 0; j < 2; ++j)
            acc[i][j] = (floatx4){0.f,0.f,0.f,0.f};

    int r  = tid >> 2;
    int kc = (tid & 3) * 16;
    int gr = row0 + r;
    int gc = col0 + r;
    const short8 z8 = {0,0,0,0,0,0,0,0};

    for (int k0 = 0; k0 < K; k0 += 64) {
        short8 a0 = z8, a1 = z8;
        if (gr < M) {
            if (amode == 2) {
                const short8* p = (const short8*)((const short*)Asrc + (size_t)gr*K + k0 + kc);
                a0 = p[0]; a1 = p[1];
            } else {
                const float4* p = (const float4*)((const float*)Asrc + (size_t)gr*K + k0 + kc);
                float4 x0 = p[0], x1 = p[1], x2 = p[2], x3 = p[3];
                a0[0]=f2bs(x0.x); a0[1]=f2bs(x0.y); a0[2]=f2bs(x0.z); a0[3]=f2bs(x0.w);
                a0[4]=f2bs(x1.x); a0[5]=f2bs(x1.y); a0[6]=f2bs(x1.z); a0[7]=f2bs(x1.w);
                a1[0]=f2bs(x2.x); a1[1]=f2bs(x2.y); a1[2]=f2bs(x2.z); a1[3]=f2bs(x2.w);
                a1[4]=f2bs(x3.x); a1[5]=f2bs(x3.y); a1[6]=f2bs(x3.z); a1[7]=f2bs(x3.w);
            }
        }
        *(short8*)&As[r*LDK + kc]     = a0;
        *(short8*)&As[r*LDK + kc + 8] = a1;
        short8 b0 = z8, b1 = z8;
        if (gc < N) {
            const short8* p = (const short8*)(Wt + (size_t)gc*K + k0 + kc);
            b0 = p[0]; b1 = p[1];
        }
        *(short8*)&Bs[r*LDK + kc]     = b0;
        *(short8*)&Bs[r*LDK + kc + 8] = b1;
        __syncthreads();
        #pragma unroll
        for (int kb = 0; kb < 64; kb += 32) {
            short8 af[2], bfr[2];
            #pragma unroll
            for (int mi = 0; mi < 2; ++mi)
                af[mi] = *(const short8*)&As[(wm*32 + mi*16 + l16)*LDK + kb + quad*8];
            #pragma unroll
            for (int ni = 0; ni < 2; ++ni)
                bfr[ni] = *(const short8*)&Bs[(wn*32 + ni*16 + l16)*LDK + kb + quad*8];
            #pragma unroll
            for (int mi = 0; mi < 2; ++mi)
                #pragma unroll
                for (int ni = 0; ni < 2; ++ni)
                    acc[mi][ni] = __builtin_amdgcn_mfma_f32_16x16x32_bf16(
                        af[mi], bfr[ni], acc[mi][ni], 0, 0, 0);
        }
        __syncthreads();
    }
    #pragma unroll
    for (int mi = 0; mi < 2; ++mi) {
        int rbase = row0 + wm*32 + mi*16 + quad*4;
        #pragma unroll
        for (int ni = 0; ni < 2; ++ni) {
            int c = col0 + wn*32 + ni*16 + l16;
            if (c >= N) continue;
            #pragma unroll
            for (int r2 = 0; r2 < 4; ++r2) {
                int rr = rbase + r2;
                if (rr >= M) continue;
                float v = acc[mi][ni][r2];
                if (bias) v += bias[c];
                if (act) v = 0.5f*v*(1.f + tanhf(0.7978845608028654f*(v + 0.044715f*v*v*v)));
                if (res) v += res[(size_t)rr*N + c];
                if (cbf) ((bf16*)Cout)[(size_t)rr*N + c] = __float2bfloat16(v);
                else     ((float*)Cout)[(size_t)rr*N + c] = v;
            }
        }
    }
}

// ---------- MFMA GEMM 128x128 with fused LN on A (value GEMM) ----------
__global__ __launch_bounds__(256) void mgemm128_kernel(
    const void* __restrict__ Asrc, const int* __restrict__ flag,
    const float2* __restrict__ stats, const float* __restrict__ g, const float* __restrict__ bvec,
    const short* __restrict__ Wt, const float* __restrict__ bias,
    bf16* __restrict__ C, int K, int N){
    __shared__ short As[128*LDK];
    __shared__ short Bs[128*LDK];
    __shared__ float gs[256], bs[256];
    int tid = threadIdx.x;
    int f = flag[0];
    int wave = tid >> 6, lane = tid & 63;
    int wm = wave >> 1, wn = wave & 1;
    int quad = lane >> 4, l16 = lane & 15;
    int row0 = blockIdx.x*128, col0 = blockIdx.y*128;
    if (tid < K) { gs[tid] = g[tid]; bs[tid] = bvec[tid]; }
    floatx4 acc[4][4];
    #pragma unroll
    for (int i = 0; i < 4; ++i)
        #pragma unroll
        for (int j = 0; j < 4; ++j)
            acc[i][j] = (floatx4){0.f,0.f,0.f,0.f};
    __syncthreads();

    for (int k0 = 0; k0 < K; k0 += 64) {
        #pragma unroll
        for (int i = 0; i < 2; ++i) {
            int idx = tid + i*256;
            int r = idx >> 2;
            int kc = (idx & 3) * 16;
            int gr = row0 + r;
            float2 st = stats[gr];
            float av[16];
            if (f) {
                const float4* p = (const float4*)((const float*)Asrc + (size_t)gr*K + k0 + kc);
                float4 x0 = p[0], x1 = p[1], x2 = p[2], x3 = p[3];
                av[0]=x0.x; av[1]=x0.y; av[2]=x0.z; av[3]=x0.w;
                av[4]=x1.x; av[5]=x1.y; av[6]=x1.z; av[7]=x1.w;
                av[8]=x2.x; av[9]=x2.y; av[10]=x2.z; av[11]=x2.w;
                av[12]=x3.x; av[13]=x3.y; av[14]=x3.z; av[15]=x3.w;
            } else {
                const short8* p = (const short8*)((const short*)Asrc + (size_t)gr*K + k0 + kc);
                short8 s0 = p[0], s1 = p[1];
                #pragma unroll
                for (int j = 0; j < 8; ++j) {
                    av[j] = bs2f(s0[j]); av[8+j] = bs2f(s1[j]);
                }
            }
            short8 a0, a1;
            #pragma unroll
            for (int j = 0; j < 16; ++j) {
                float v = (av[j] - st.x) * st.y * gs[k0+kc+j] + bs[k0+kc+j];
                if (j < 8) a0[j] = f2bs(v); else a1[j-8] = f2bs(v);
            }
            *(short8*)&As[r*LDK + kc]     = a0;
            *(short8*)&As[r*LDK + kc + 8] = a1;
            int gc = col0 + r;
            const short8* pb = (const short8*)(Wt + (size_t)gc*K + k0 + kc);
            *(short8*)&Bs[r*LDK + kc]     = pb[0];
            *(short8*)&Bs[r*LDK + kc + 8] = pb[1];
        }
        __syncthreads();
        #pragma unroll
        for (int kb = 0; kb < 64; kb += 32) {
            short8 af[4], bfr[4];
            #pragma unroll
            for (int mi = 0; mi < 4; ++mi)
                af[mi] = *(const short8*)&As[(wm*64 + mi*16 + l16)*LDK + kb + quad*8];
            #pragma unroll
            for (int ni = 0; ni < 4; ++ni)
                bfr[ni] = *(const short8*)&Bs[(wn*64 + ni*16 + l16)*LDK + kb + quad*8];
            #pragma unroll
            for (int mi = 0; mi < 4; ++mi)
                #pragma unroll
                for (int ni = 0; ni < 4; ++ni)
                    acc[mi][ni] = __builtin_amdgcn_mfma_f32_16x16x32_bf16(
                        af[mi], bfr[ni], acc[mi][ni], 0, 0, 0);
        }
        __syncthreads();
    }
    #pragma unroll
    for (int mi = 0; mi < 4; ++mi) {
        int rbase = row0 + wm*64 + mi*16 + quad*4;
        #pragma unroll
        for (int ni = 0; ni < 4; ++ni) {
            int c = col0 + wn*64 + ni*16 + l16;
            float bv = bias[c];
            #pragma unroll
            for (int r2 = 0; r2 < 4; ++r2)
                C[(size_t)(rbase + r2)*N + c] = __float2bfloat16(acc[mi][ni][r2] + bv);
        }
    }
}

// ---------- attention stage 1: S = (Q*scale) @ K^T, bf16, cols padded to 1024 ----------
// grid (16 qtile, 16 ktile, 16 hh); S[hh][1000][1024]
__global__ __launch_bounds__(256) void sattn_kernel(const short* __restrict__ qkv,
                                                    short* __restrict__ S, int half){
    int hh = blockIdx.z;
    int nh = half*16 + hh;
    int n = nh >> 3, h = nh & 7;
    int q0 = blockIdx.x * 64, k0 = blockIdx.y * 64;
    __shared__ short As[64*40];
    __shared__ short Bs[64*40];
    int tid = threadIdx.x;
    int r = tid >> 2, c = (tid & 3) * 8;
    const short8 z8 = {0,0,0,0,0,0,0,0};
    {
        int gq = q0 + r;
        short8 a = z8;
        if (gq < LQ) {
            short8 s = *(const short8*)(qkv + ((size_t)(n*LQ+gq))*768 + h*32 + c);
            #pragma unroll
            for (int j = 0; j < 8; ++j) a[j] = f2bs(bs2f(s[j]) * ATT_SCALE);
        }
        *(short8*)&As[r*40 + c] = a;
        int gk = k0 + r;
        short8 b = z8;
        if (gk < LQ)
            b = *(const short8*)(qkv + ((size_t)(n*LQ+gk))*768 + 256 + h*32 + c);
        *(short8*)&Bs[r*40 + c] = b;
    }
    __syncthreads();
    int wave = tid >> 6, lane = tid & 63;
    int wm = wave >> 1, wn = wave & 1;
    int quad = lane >> 4, l16 = lane & 15;
    floatx4 acc[2][2];
    #pragma unroll
    for (int mi = 0; mi < 2; ++mi) {
        short8 af = *(const short8*)&As[(wm*32 + mi*16 + l16)*40 + quad*8];
        #pragma unroll
        for (int ni = 0; ni < 2; ++ni) {
            short8 bfr = *(const short8*)&Bs[(wn*32 + ni*16 + l16)*40 + quad*8];
            acc[mi][ni] = __builtin_amdgcn_mfma_f32_16x16x32_bf16(
                af, bfr, (floatx4){0.f,0.f,0.f,0.f}, 0, 0, 0);
        }
    }
    #pragma unroll
    for (int mi = 0; mi < 2; ++mi) {
        int rbase = q0 + wm*32 + mi*16 + quad*4;
        #pragma unroll
        for (int ni = 0; ni < 2; ++ni) {
            int col = k0 + wn*32 + ni*16 + l16;
            #pragma unroll
            for (int r2 = 0; r2 < 4; ++r2) {
                int row = rbase + r2;
                if (row < LQ)
                    S[((size_t)hh*LQ + row)*1024 + col] = f2bs(acc[mi][ni][r2]);
            }
        }
    }
}

// ---------- attention stage 2: per-row (max, 1/sumexp), read-only ----------
// grid (250, 16), block 256 = 4 waves, one wave per row; lane covers 16 cols
__global__ __launch_bounds__(256) void rowstat_kernel(const short* __restrict__ S,
                                                      float2* __restrict__ ml){
    int hh = blockIdx.y;
    int wave = threadIdx.x >> 6, lane = threadIdx.x & 63;
    int q = blockIdx.x*4 + wave;     // < 1000 always
    const unsigned short* row = (const unsigned short*)(S + ((size_t)hh*LQ + q)*1024);
    int base = lane*16;
    float v[16];
    #pragma unroll
    for (int c = 0; c < 4; ++c) {
        ushort4 u = *(const ushort4*)(row + base + c*4);
        v[c*4]   = bs2f((short)u.x); v[c*4+1] = bs2f((short)u.y);
        v[c*4+2] = bs2f((short)u.z); v[c*4+3] = bs2f((short)u.w);
    }
    float m = -3.0e38f;
    #pragma unroll
    for (int j = 0; j < 16; ++j) if (base + j < LQ) m = fmaxf(m, v[j]);
    #pragma unroll
    for (int o = 32; o; o >>= 1) m = fmaxf(m, __shfl_xor(m, o, 64));
    float s = 0.f;
    #pragma unroll
    for (int j = 0; j < 16; ++j) if (base + j < LQ) s += __expf(v[j] - m);
    #pragma unroll
    for (int o = 32; o; o >>= 1) s += __shfl_xor(s, o, 64);
    if (lane == 0) ml[hh*LQ + q] = make_float2(m, 1.f/s);
}

// ---------- attention stage 3: O = softmax(S) @ V, normalization fused in staging ----------
// grid (16 qtile, 16 hh), block 256 (4 waves, 16 q-rows each)
__global__ __launch_bounds__(256) void pv2_kernel(const short* __restrict__ S,
                                                  const float2* __restrict__ ml,
                                                  const short* __restrict__ qkv,
                                                  float* __restrict__ out, int half){
    int hh = blockIdx.y;
    int nh = half*16 + hh;
    int n = nh >> 3, h = nh & 7;
    int q0 = blockIdx.x * 64;
    __shared__ short Ps[64*72];
    __shared__ short VsT[32*72];
    int tid = threadIdx.x;
    int wave = tid >> 6, lane = tid & 63;
    int quad = lane >> 4, l16 = lane & 15;
    int r = tid >> 2;
    int cp = (tid & 3) * 16;
    int cv = (tid & 3) * 8;
    const short8 z8 = {0,0,0,0,0,0,0,0};
    floatx4 acc[2];
    acc[0] = (floatx4){0.f,0.f,0.f,0.f};
    acc[1] = (floatx4){0.f,0.f,0.f,0.f};

    int gq = q0 + r;
    float mrow = 0.f, invl = 0.f;
    bool rok = gq < LQ;
    if (rok) { float2 t = ml[hh*LQ + gq]; mrow = t.x; invl = t.y; }

    for (int k0 = 0; k0 < 1024; k0 += 64) {
        short8 q0v = z8, q1v = z8;
        if (rok) {
            const short* sp = S + ((size_t)hh*LQ + gq)*1024 + k0 + cp;
            short8 p0 = *(const short8*)sp;
            short8 p1 = *(const short8*)(sp + 8);
            #pragma unroll
            for (int j = 0; j < 8; ++j) {
                int c0 = k0 + cp + j, c1 = c0 + 8;
                float pv0 = (c0 < LQ) ? __expf(bs2f(p0[j]) - mrow) * invl : 0.f;
                float pv1 = (c1 < LQ) ? __expf(bs2f(p1[j]) - mrow) * invl : 0.f;
                q0v[j] = f2bs(pv0); q1v[j] = f2bs(pv1);
            }
        }
        *(short8*)&Ps[r*72 + cp]     = q0v;
        *(short8*)&Ps[r*72 + cp + 8] = q1v;
        int gk = k0 + r;
        short8 vv = z8;
        if (gk < LQ)
            vv = *(const short8*)(qkv + ((size_t)(n*LQ+gk))*768 + 512 + h*32 + cv);
        #pragma unroll
        for (int j = 0; j < 8; ++j) VsT[(cv+j)*72 + r] = vv[j];
        __syncthreads();
        #pragma unroll
        for (int kb = 0; kb < 64; kb += 32) {
            short8 af = *(const short8*)&Ps[(wave*16 + l16)*72 + kb + quad*8];
            #pragma unroll
            for (int ni = 0; ni < 2; ++ni) {
                short8 bfr = *(const short8*)&VsT[(ni*16 + l16)*72 + kb + quad*8];
                acc[ni] = __builtin_amdgcn_mfma_f32_16x16x32_bf16(af, bfr, acc[ni], 0, 0, 0);
            }
        }
        __syncthreads();
    }
    #pragma unroll
    for (int ni = 0; ni < 2; ++ni)
        #pragma unroll
        for (int r2 = 0; r2 < 4; ++r2) {
            int row = q0 + wave*16 + quad*4 + r2;
            if (row < LQ)
                out[((size_t)(n*LQ+row))*256 + h*32 + ni*16 + l16] = acc[ni][r2];
        }
}

// ---------- deformable sampling with fused aw-softmax + shuffle broadcasts ----------
__global__ __launch_bounds__(256) void sample2_kernel(
        const bf16* __restrict__ value, const float* __restrict__ offaw,
        const float* __restrict__ cp, float* __restrict__ out){
    int nq = blockIdx.x;
    int n = nq / LQ;
    int d = threadIdx.x & 31, h = threadIdx.x >> 5;
    float cx = cp[nq*2], cy = cp[nq*2+1];
    const float* rowp = offaw + (size_t)nq*480;
    float o0 = rowp[h*40 + d];
    float o1 = (d < 8) ? rowp[h*40 + 32 + d] : 0.f;
    float logit = (d < 20) ? rowp[320 + h*20 + d] : -3.0e38f;
    float mx = logit;
    #pragma unroll
    for (int off = 16; off; off >>= 1) mx = fmaxf(mx, __shfl_xor(mx, off, 32));
    float p = (d < 20) ? __expf(logit - mx) : 0.f;
    float sm = p;
    #pragma unroll
    for (int off = 16; off; off >>= 1) sm += __shfl_xor(sm, off, 32);
    p *= (1.f / sm);

    const int HW[5] = {128,64,32,16,8};
    const int ST[5] = {0,16384,20480,21504,21760};
    float acc = 0.f;
    #pragma unroll
    for (int l = 0; l < 5; ++l) {
        int hw = HW[l];
        float fhw = (float)hw;
        size_t vb = ((size_t)n*LIN + ST[l]) * 256 + h*32 + d;
        #pragma unroll
        for (int pi = 0; pi < 4; ++pi) {
            const int idx = l*4 + pi;
            float w  = __shfl(p, idx, 32);
            float ox = (2*idx < 32)   ? __shfl(o0, 2*idx, 32)   : __shfl(o1, 2*idx-32, 32);
            float oy = (2*idx+1 < 32) ? __shfl(o0, 2*idx+1, 32) : __shfl(o1, 2*idx+1-32, 32);
            float gx = cx*fhw + ox - 0.5f;
            float gy = cy*fhw + oy - 0.5f;
            float x0f = floorf(gx), y0f = floorf(gy);
            float lx = gx - x0f, ly = gy - y0f;
            int x0 = (int)x0f, y0 = (int)y0f;
            float s = 0.f;
            if ((unsigned)y0     < (unsigned)hw && (unsigned)x0     < (unsigned)hw)
                s += (1.f-ly)*(1.f-lx)*__bfloat162float(value[vb + (size_t)(y0*hw + x0)*256]);
            if ((unsigned)y0     < (unsigned)hw && (unsigned)(x0+1) < (unsigned)hw)
                s += (1.f-ly)*lx      *__bfloat162float(value[vb + (size_t)(y0*hw + x0+1)*256]);
            if ((unsigned)(y0+1) < (unsigned)hw && (unsigned)x0     < (unsigned)hw)
                s += ly*(1.f-lx)      *__bfloat162float(value[vb + (size_t)((y0+1)*hw + x0)*256]);
            if ((unsigned)(y0+1) < (unsigned)hw && (unsigned)(x0+1) < (unsigned)hw)
                s += ly*lx            *__bfloat162float(value[vb + (size_t)((y0+1)*hw + x0+1)*256]);
            acc += w * s;
        }
    }
    out[(size_t)nq*256 + h*32 + d] = acc;
}

// ---------- final store ----------
__global__ void final_kernel(const float* __restrict__ in, void* __restrict__ out,
                             int n, const int* __restrict__ flag){
    int f = flag[0];
    int i = blockIdx.x*256 + threadIdx.x;
    if (i >= n) return;
    float v = in[i];
    if (!isfinite(v)) v = 0.f;
    if (f) ((float*)out)[i] = v;
    else   ((bf16*)out)[i] = __float2bfloat16(v);
}

extern "C" void kernel_launch(void* const* d_in, const int* in_sizes, int n_in,
                              void* d_out, int out_size, void* d_ws, size_t ws_size,
                              hipStream_t stream){
    const void* x_raw  = d_in[0];
    const void* src    = d_in[1];
    const void* cp_raw = d_in[2];
    char* ws = (char*)d_ws;
    size_t off = 0;
    auto alloc = [&](size_t bytes){ size_t p = off; off += (bytes + 255) & ~(size_t)255; return p; };
    int*   flag  = (int*)(ws + alloc(256));
    float* xf    = (float*)(ws + alloc((size_t)ROWS_X*DIM*4));
    float* pe    = (float*)(ws + alloc((size_t)ROWS_X*DIM*4));
    float* nbuf  = (float*)(ws + alloc((size_t)ROWS_X*DIM*4));
    float* tmp   = (float*)(ws + alloc((size_t)ROWS_X*DIM*4));
    bf16*  qkv   = (bf16*)(ws + alloc((size_t)ROWS_X*768*2));
    bf16*  ffh   = (bf16*)(ws + alloc((size_t)ROWS_X*MLPD*2));
    float* offaw = (float*)(ws + alloc((size_t)ROWS_X*480*4));
    float2* stats = (float2*)(ws + alloc((size_t)ROWS_SRC*8));
    float* cpf   = (float*)(ws + alloc((size_t)ROWS_X*2*4));
    float* oab   = (float*)(ws + alloc((size_t)2*480*4));
    float2* ml   = (float2*)(ws + alloc((size_t)16*LQ*8));
    const int sidx[13] = {5,6,7,8,11,12,13,19,21,22,23,25,27};
    const int ssz[13]  = {512,256,512,512,512,512,512,512,512,512,512,1024,512};
    float* sp[13];
    for (int j = 0; j < 13; ++j) sp[j] = (float*)(ws + alloc((size_t)ssz[j]*4));
    short* qkvT = (short*)(ws + alloc((size_t)2*768*256*2));
    short* outT = (short*)(ws + alloc((size_t)2*256*256*2));
    short* oawT = (short*)(ws + alloc((size_t)2*480*256*2));
    short* valT = (short*)(ws + alloc((size_t)2*256*256*2));
    short* opT  = (short*)(ws + alloc((size_t)2*256*256*2));
    short* ff1T = (short*)(ws + alloc((size_t)2*512*256*2));
    short* ff2T = (short*)(ws + alloc((size_t)2*256*512*2));
    bf16*  val  = (bf16*)(ws + alloc((size_t)ROWS_SRC*DIM*2));
    // S (16 nh x 1000 x 1024 bf16 = 31.25 MB) aliases val (44.7 MB):
    // lifetimes are disjoint (S: attention phase; val: mgemm128->sample2 phase).
    short* Sbuf = (short*)val;
    (void)ws_size; (void)in_sizes; (void)n_in; (void)out_size;

    detect_kernel<<<1, 256, 0, stream>>>(x_raw, flag);
    conv_kernel<<<(ROWS_X*DIM+255)/256, 256, 0, stream>>>(x_raw, xf, ROWS_X*DIM, flag);
    conv_kernel<<<(ROWS_X*2+255)/256, 256, 0, stream>>>(cp_raw, cpf, ROWS_X*2, flag);
    PTab pt;
    for (int j = 0; j < 13; ++j) { pt.src[j] = d_in[sidx[j]]; pt.dst[j] = sp[j]; pt.n[j] = ssz[j]; }
    convs_kernel<<<dim3(4,13), 256, 0, stream>>>(pt, flag);
    catb_kernel<<<dim3(2,2), 256, 0, stream>>>(d_in[15], d_in[17], flag, oab);
    wtrans_kernel<<<dim3(8,24,2), 256, 0, stream>>>(d_in[9],  flag, qkvT, 256, 768, 768, 0);
    wtrans_kernel<<<dim3(8,8,2),  256, 0, stream>>>(d_in[10], flag, outT, 256, 256, 256, 0);
    wtrans_kernel<<<dim3(8,10,2), 256, 0, stream>>>(d_in[14], flag, oawT, 256, 320, 480, 0);
    wtrans_kernel<<<dim3(8,5,2),  256, 0, stream>>>(d_in[16], flag, oawT, 256, 160, 480, 320);
    wtrans_kernel<<<dim3(8,8,2),  256, 0, stream>>>(d_in[18], flag, valT, 256, 256, 256, 0);
    wtrans_kernel<<<dim3(8,8,2),  256, 0, stream>>>(d_in[20], flag, opT,  256, 256, 256, 0);
    wtrans_kernel<<<dim3(8,16,2), 256, 0, stream>>>(d_in[24], flag, ff1T, 256, 512, 512, 0);
    wtrans_kernel<<<dim3(16,8,2), 256, 0, stream>>>(d_in[26], flag, ff2T, 512, 256, 256, 0);

    float* pos_w = sp[0];  float* pos_b = sp[1];
    float* ln1_g = sp[2];  float* ln1_b = sp[3];
    float* out_b = sp[4];
    float* ln2_g = sp[5];  float* ln2_b = sp[6];
    float* val_b = sp[7];  float* op_b  = sp[8];
    float* ln3_g = sp[9];  float* ln3_b = sp[10];
    float* ff_b1 = sp[11]; float* ff_b2 = sp[12];

    pe_kernel<<<ROWS_X, 256, 0, stream>>>(cpf, pos_w, pos_b, pe);
    stats2_kernel<<<ROWS_SRC/4, 256, 0, stream>>>(src, flag, stats);

    int gmx = (ROWS_X + 63) / 64;   // 63
    for (int i = 0; i < 2; ++i) {
        // --- self attention (MFMA, materialized S, 2 halves of 16 nh) ---
        ln_kernel<<<ROWS_X, 256, 0, stream>>>(xf, pe, nullptr, ln1_g + i*DIM, ln1_b + i*DIM, nbuf);
        mgemm_kernel<<<dim3(gmx,12), 256, 0, stream>>>(
            nbuf, qkvT + (size_t)i*768*256, nullptr, nullptr, qkv, ROWS_X, 256, 768, 0, 0, 1);
        for (int half = 0; half < 2; ++half) {
            sattn_kernel<<<dim3(16,16,16), 256, 0, stream>>>((const short*)qkv, Sbuf, half);
            rowstat_kernel<<<dim3(250,16), 256, 0, stream>>>(Sbuf, ml);
            pv2_kernel<<<dim3(16,16), 256, 0, stream>>>(Sbuf, ml, (const short*)qkv, tmp, half);
        }
        mgemm_kernel<<<dim3(gmx,4), 256, 0, stream>>>(
            tmp, outT + (size_t)i*256*256, out_b + i*DIM, xf, xf, ROWS_X, 256, 256, 0, 0, 0);
        // --- deformable cross attention ---
        mgemm128_kernel<<<dim3(ROWS_SRC/128, 2), 256, 0, stream>>>(
            src, flag, stats, ln2_g + i*DIM, ln2_b + i*DIM,
            valT + (size_t)i*256*256, val_b + i*DIM, val, 256, 256);
        ln_kernel<<<ROWS_X, 256, 0, stream>>>(xf, nullptr, pe, ln2_g + i*DIM, ln2_b + i*DIM, nbuf);
        mgemm_kernel<<<dim3(gmx,8), 256, 0, stream>>>(
            nbuf, oawT + (size_t)i*480*256, oab + i*480, nullptr, offaw, ROWS_X, 256, 480, 0, 0, 0);
        sample2_kernel<<<ROWS_X, 256, 0, stream>>>(val, offaw, cpf, tmp);
        mgemm_kernel<<<dim3(gmx,4), 256, 0, stream>>>(
            tmp, opT + (size_t)i*256*256, op_b + i*DIM, xf, xf, ROWS_X, 256, 256, 0, 0, 0);
        // --- feedforward ---
        ln_kernel<<<ROWS_X, 256, 0, stream>>>(xf, nullptr, nullptr, ln3_g + i*DIM, ln3_b + i*DIM, nbuf);
        mgemm_kernel<<<dim3(gmx,8), 256, 0, stream>>>(
            nbuf, ff1T + (size_t)i*512*256, ff_b1 + i*MLPD, nullptr, ffh, ROWS_X, 256, 512, 1, 0, 1);
        mgemm_kernel<<<dim3(gmx,4), 256, 0, stream>>>(
            ffh, ff2T + (size_t)i*256*512, ff_b2 + i*DIM, xf, xf, ROWS_X, 512, 256, 0, 2, 0);
    }
    final_kernel<<<(ROWS_X*DIM+255)/256, 256, 0, stream>>>(xf, d_out, ROWS_X*DIM, flag);
}

// Round 10
// 740.521 us; speedup vs baseline: 1.3424x; 1.0366x over previous
//
#include <hip/hip_runtime.h>
#include <hip/hip_bf16.h>
#include <math.h>

#define DIM 256
#define NB 4
#define LQ 1000
#define MLPD 512
#define LIN 21824
#define ROWS_X 4000
#define ROWS_SRC 87296
#define ATT_SCALE 0.17677669529663687f  /* 32^-0.5 */
#define LDK 72   /* padded LDS row (bf16 elems): 144 B, 16B-aligned */

typedef __hip_bfloat16 bf16;
typedef __attribute__((ext_vector_type(8))) short short8;
typedef __attribute__((ext_vector_type(4))) float floatx4;

__device__ __forceinline__ float rdv(const void* p, int f, size_t i){
    if (f) return ((const float*)p)[i];
    unsigned u = ((unsigned)((const unsigned short*)p)[i]) << 16;
    union { unsigned u; float f; } c; c.u = u; return c.f;
}
__device__ __forceinline__ short f2bs(float v){
    bf16 h = __float2bfloat16(v);
    return *reinterpret_cast<short*>(&h);
}
__device__ __forceinline__ float bs2f(short s){
    union { unsigned u; float f; } c; c.u = ((unsigned)(unsigned short)s) << 16; return c.f;
}

// ---------- dtype detect ----------
__global__ void detect_kernel(const void* __restrict__ x, int* __restrict__ flag){
    const unsigned short* u = (const unsigned short*)x;
    int t = threadIdx.x;
    bool hit = false;
    #pragma unroll
    for (int k = 0; k < 4; ++k) {
        unsigned short b = u[(t*4 + k)*2];
        union { unsigned u; float f; } c; c.u = ((unsigned)b) << 16;
        if (!(fabsf(c.f) <= 1000.f)) hit = true;
    }
    unsigned long long m = __ballot(hit);
    __shared__ unsigned long long red[4];
    if ((t & 63) == 0) red[t >> 6] = m;
    __syncthreads();
    if (t == 0) flag[0] = ((red[0]|red[1]|red[2]|red[3]) != 0ULL) ? 1 : 0;
}

__global__ void conv_kernel(const void* __restrict__ in, float* __restrict__ out,
                            int n, const int* __restrict__ flag){
    int f = flag[0];
    int i = blockIdx.x*256 + threadIdx.x;
    if (i < n) out[i] = rdv(in, f, i);
}

// ---------- fused small-param conversions ----------
struct PTab { const void* src[13]; float* dst[13]; int n[13]; };
__global__ void convs_kernel(PTab t, const int* __restrict__ flag){
    int f = flag[0];
    int j = blockIdx.y;
    int i = blockIdx.x*256 + threadIdx.x;
    if (i < t.n[j]) t.dst[j][i] = rdv(t.src[j], f, i);
}

// ---------- concat off_b|aw_b into oab[2][480] ----------
__global__ void catb_kernel(const void* __restrict__ offb, const void* __restrict__ awb,
                            const int* __restrict__ flag, float* __restrict__ oab){
    int f = flag[0];
    int layer = blockIdx.y;
    int idx = blockIdx.x*256 + threadIdx.x;
    if (idx >= 480) return;
    float v = (idx < 320) ? rdv(offb, f, (size_t)layer*320 + idx)
                          : rdv(awb,  f, (size_t)layer*160 + idx - 320);
    oab[layer*480 + idx] = v;
}

// ---------- weight transpose: W[b][K][N] -> Wt[b][ldout][K] bf16 at row offset ----------
__global__ void wtrans_kernel(const void* __restrict__ W, const int* __restrict__ flag,
                              short* __restrict__ Wt, int K, int N, int ldout, int rowoff){
    int f = flag[0];
    int b = blockIdx.z;
    __shared__ float t[32][33];
    int k0 = blockIdx.x*32, n0 = blockIdx.y*32;
    int tx = threadIdx.x & 31, ty = threadIdx.x >> 5;
    size_t base = (size_t)b * K * N;
    for (int i = ty; i < 32; i += 8) {
        int k = k0 + i, n = n0 + tx;
        t[i][tx] = (k < K && n < N) ? rdv(W, f, base + (size_t)k*N + n) : 0.f;
    }
    __syncthreads();
    for (int i = ty; i < 32; i += 8) {
        int n = n0 + i, k = k0 + tx;
        if (n < N && k < K)
            Wt[(size_t)b*ldout*K + (size_t)(rowoff+n)*K + k] = f2bs(t[tx][i]);
    }
}

// ---------- pe ----------
__global__ void pe_kernel(const float* __restrict__ cp, const float* __restrict__ pw,
                          const float* __restrict__ pb, float* __restrict__ pe){
    int row = blockIdx.x, t = threadIdx.x;
    float cx = cp[row*2], cy = cp[row*2+1];
    pe[(size_t)row*DIM + t] = cx*pw[t] + cy*pw[DIM+t] + pb[t];
}

// ---------- per-row stats of src: one wave per row, shuffle-only ----------
__global__ __launch_bounds__(256) void stats2_kernel(const void* __restrict__ src,
                                                     const int* __restrict__ flag,
                                                     float2* __restrict__ stats){
    int f = flag[0];
    int wave = threadIdx.x >> 6, lane = threadIdx.x & 63;
    int row = blockIdx.x*4 + wave;
    float v0, v1, v2, v3;
    if (f) {
        float4 x = *(const float4*)((const float*)src + (size_t)row*DIM + lane*4);
        v0 = x.x; v1 = x.y; v2 = x.z; v3 = x.w;
    } else {
        ushort4 u = *(const ushort4*)((const unsigned short*)src + (size_t)row*DIM + lane*4);
        v0 = bs2f((short)u.x); v1 = bs2f((short)u.y);
        v2 = bs2f((short)u.z); v3 = bs2f((short)u.w);
    }
    float s  = v0 + v1 + v2 + v3;
    float s2 = v0*v0 + v1*v1 + v2*v2 + v3*v3;
    #pragma unroll
    for (int o = 32; o; o >>= 1) {
        s  += __shfl_xor(s,  o, 64);
        s2 += __shfl_xor(s2, o, 64);
    }
    if (lane == 0) {
        float mean = s * (1.f/DIM);
        float var  = s2 * (1.f/DIM) - mean*mean;
        stats[row] = make_float2(mean, rsqrtf(var + 1e-5f));
    }
}

// ---------- per-row stats of fp32 x [+pre]: one wave per row ----------
__global__ __launch_bounds__(256) void xstats_kernel(const float* __restrict__ a,
                                                     const float* __restrict__ pre,
                                                     float2* __restrict__ st){
    int wave = threadIdx.x >> 6, lane = threadIdx.x & 63;
    int row = blockIdx.x*4 + wave;
    float4 x = *(const float4*)(a + (size_t)row*DIM + lane*4);
    if (pre) {
        float4 p = *(const float4*)(pre + (size_t)row*DIM + lane*4);
        x.x += p.x; x.y += p.y; x.z += p.z; x.w += p.w;
    }
    float s  = x.x + x.y + x.z + x.w;
    float s2 = x.x*x.x + x.y*x.y + x.z*x.z + x.w*x.w;
    #pragma unroll
    for (int o = 32; o; o >>= 1) {
        s  += __shfl_xor(s,  o, 64);
        s2 += __shfl_xor(s2, o, 64);
    }
    if (lane == 0) {
        float mean = s * (1.f/DIM);
        float var  = s2 * (1.f/DIM) - mean*mean;
        st[row] = make_float2(mean, rsqrtf(var + 1e-5f));
    }
}

// ---------- MFMA GEMM 64x64: C = A' @ Wt^T (+bias)(gelu?)(+res) ----------
// AMODE: 0 = A fp32; 2 = A bf16; 3 = A fp32 with fused LN:
//   A' = (A [+Apre] - m)*rstd*ag + ab [+Apost]
template<int AMODE>
__global__ __launch_bounds__(256) void mgemm_kernel(
    const void* __restrict__ Asrc,
    const float2* __restrict__ ast, const float* __restrict__ ag, const float* __restrict__ ab,
    const float* __restrict__ Apre, const float* __restrict__ Apost,
    const short* __restrict__ Wt, const float* __restrict__ bias, const float* res,
    void* Cout, int M, int K, int N, int act, int cbf){
    __shared__ short As[64*LDK];
    __shared__ short Bs[64*LDK];
    int tid = threadIdx.x;
    int wave = tid >> 6, lane = tid & 63;
    int wm = wave >> 1, wn = wave & 1;
    int quad = lane >> 4, l16 = lane & 15;
    int row0 = blockIdx.x*64, col0 = blockIdx.y*64;
    floatx4 acc[2][2];
    #pragma unroll
    for (int i = 0; i < 2; ++i)
        #pragma unroll
        for (int j = 0; j < 2; ++j)
            acc[i][j] = (floatx4){0.f,0.f,0.f,0.f};

    int r  = tid >> 2;
    int kc = (tid & 3) * 16;
    int gr = row0 + r;
    int gc = col0 + r;
    const short8 z8 = {0,0,0,0,0,0,0,0};

    for (int k0 = 0; k0 < K; k0 += 64) {
        short8 a0 = z8, a1 = z8;
        if (gr < M) {
            if (AMODE == 2) {
                const short8* p = (const short8*)((const short*)Asrc + (size_t)gr*K + k0 + kc);
                a0 = p[0]; a1 = p[1];
            } else {
                const float4* p = (const float4*)((const float*)Asrc + (size_t)gr*K + k0 + kc);
                float4 x0 = p[0], x1 = p[1], x2 = p[2], x3 = p[3];
                float av[16] = {x0.x,x0.y,x0.z,x0.w, x1.x,x1.y,x1.z,x1.w,
                                x2.x,x2.y,x2.z,x2.w, x3.x,x3.y,x3.z,x3.w};
                if (AMODE == 3) {
                    if (Apre) {
                        const float4* q = (const float4*)(Apre + (size_t)gr*K + k0 + kc);
                        float4 p0 = q[0], p1 = q[1], p2 = q[2], p3 = q[3];
                        float pv[16] = {p0.x,p0.y,p0.z,p0.w, p1.x,p1.y,p1.z,p1.w,
                                        p2.x,p2.y,p2.z,p2.w, p3.x,p3.y,p3.z,p3.w};
                        #pragma unroll
                        for (int j = 0; j < 16; ++j) av[j] += pv[j];
                    }
                    float2 st = ast[gr];
                    const float4* gp = (const float4*)(ag + k0 + kc);
                    const float4* bp = (const float4*)(ab + k0 + kc);
                    float4 g0 = gp[0], g1 = gp[1], g2 = gp[2], g3 = gp[3];
                    float4 b0 = bp[0], b1 = bp[1], b2 = bp[2], b3 = bp[3];
                    float gv[16] = {g0.x,g0.y,g0.z,g0.w, g1.x,g1.y,g1.z,g1.w,
                                    g2.x,g2.y,g2.z,g2.w, g3.x,g3.y,g3.z,g3.w};
                    float bv[16] = {b0.x,b0.y,b0.z,b0.w, b1.x,b1.y,b1.z,b1.w,
                                    b2.x,b2.y,b2.z,b2.w, b3.x,b3.y,b3.z,b3.w};
                    #pragma unroll
                    for (int j = 0; j < 16; ++j)
                        av[j] = (av[j] - st.x)*st.y*gv[j] + bv[j];
                    if (Apost) {
                        const float4* q = (const float4*)(Apost + (size_t)gr*K + k0 + kc);
                        float4 p0 = q[0], p1 = q[1], p2 = q[2], p3 = q[3];
                        float pv[16] = {p0.x,p0.y,p0.z,p0.w, p1.x,p1.y,p1.z,p1.w,
                                        p2.x,p2.y,p2.z,p2.w, p3.x,p3.y,p3.z,p3.w};
                        #pragma unroll
                        for (int j = 0; j < 16; ++j) av[j] += pv[j];
                    }
                }
                #pragma unroll
                for (int j = 0; j < 8; ++j) { a0[j] = f2bs(av[j]); a1[j] = f2bs(av[8+j]); }
            }
        }
        *(short8*)&As[r*LDK + kc]     = a0;
        *(short8*)&As[r*LDK + kc + 8] = a1;
        short8 b0 = z8, b1 = z8;
        if (gc < N) {
            const short8* p = (const short8*)(Wt + (size_t)gc*K + k0 + kc);
            b0 = p[0]; b1 = p[1];
        }
        *(short8*)&Bs[r*LDK + kc]     = b0;
        *(short8*)&Bs[r*LDK + kc + 8] = b1;
        __syncthreads();
        #pragma unroll
        for (int kb = 0; kb < 64; kb += 32) {
            short8 af[2], bfr[2];
            #pragma unroll
            for (int mi = 0; mi < 2; ++mi)
                af[mi] = *(const short8*)&As[(wm*32 + mi*16 + l16)*LDK + kb + quad*8];
            #pragma unroll
            for (int ni = 0; ni < 2; ++ni)
                bfr[ni] = *(const short8*)&Bs[(wn*32 + ni*16 + l16)*LDK + kb + quad*8];
            #pragma unroll
            for (int mi = 0; mi < 2; ++mi)
                #pragma unroll
                for (int ni = 0; ni < 2; ++ni)
                    acc[mi][ni] = __builtin_amdgcn_mfma_f32_16x16x32_bf16(
                        af[mi], bfr[ni], acc[mi][ni], 0, 0, 0);
        }
        __syncthreads();
    }
    #pragma unroll
    for (int mi = 0; mi < 2; ++mi) {
        int rbase = row0 + wm*32 + mi*16 + quad*4;
        #pragma unroll
        for (int ni = 0; ni < 2; ++ni) {
            int c = col0 + wn*32 + ni*16 + l16;
            if (c >= N) continue;
            #pragma unroll
            for (int r2 = 0; r2 < 4; ++r2) {
                int rr = rbase + r2;
                if (rr >= M) continue;
                float v = acc[mi][ni][r2];
                if (bias) v += bias[c];
                if (act) v = 0.5f*v*(1.f + tanhf(0.7978845608028654f*(v + 0.044715f*v*v*v)));
                if (res) v += res[(size_t)rr*N + c];
                if (cbf) ((bf16*)Cout)[(size_t)rr*N + c] = __float2bfloat16(v);
                else     ((float*)Cout)[(size_t)rr*N + c] = v;
            }
        }
    }
}

// ---------- MFMA GEMM 128x128 with fused LN on A (value GEMM) ----------
__global__ __launch_bounds__(256) void mgemm128_kernel(
    const void* __restrict__ Asrc, const int* __restrict__ flag,
    const float2* __restrict__ stats, const float* __restrict__ g, const float* __restrict__ bvec,
    const short* __restrict__ Wt, const float* __restrict__ bias,
    bf16* __restrict__ C, int K, int N){
    __shared__ short As[128*LDK];
    __shared__ short Bs[128*LDK];
    __shared__ float gs[256], bs[256];
    int tid = threadIdx.x;
    int f = flag[0];
    int wave = tid >> 6, lane = tid & 63;
    int wm = wave >> 1, wn = wave & 1;
    int quad = lane >> 4, l16 = lane & 15;
    int row0 = blockIdx.x*128, col0 = blockIdx.y*128;
    if (tid < K) { gs[tid] = g[tid]; bs[tid] = bvec[tid]; }
    floatx4 acc[4][4];
    #pragma unroll
    for (int i = 0; i < 4; ++i)
        #pragma unroll
        for (int j = 0; j < 4; ++j)
            acc[i][j] = (floatx4){0.f,0.f,0.f,0.f};
    __syncthreads();

    for (int k0 = 0; k0 < K; k0 += 64) {
        #pragma unroll
        for (int i = 0; i < 2; ++i) {
            int idx = tid + i*256;
            int r = idx >> 2;
            int kc = (idx & 3) * 16;
            int gr = row0 + r;
            float2 st = stats[gr];
            float av[16];
            if (f) {
                const float4* p = (const float4*)((const float*)Asrc + (size_t)gr*K + k0 + kc);
                float4 x0 = p[0], x1 = p[1], x2 = p[2], x3 = p[3];
                av[0]=x0.x; av[1]=x0.y; av[2]=x0.z; av[3]=x0.w;
                av[4]=x1.x; av[5]=x1.y; av[6]=x1.z; av[7]=x1.w;
                av[8]=x2.x; av[9]=x2.y; av[10]=x2.z; av[11]=x2.w;
                av[12]=x3.x; av[13]=x3.y; av[14]=x3.z; av[15]=x3.w;
            } else {
                const short8* p = (const short8*)((const short*)Asrc + (size_t)gr*K + k0 + kc);
                short8 s0 = p[0], s1 = p[1];
                #pragma unroll
                for (int j = 0; j < 8; ++j) {
                    av[j] = bs2f(s0[j]); av[8+j] = bs2f(s1[j]);
                }
            }
            short8 a0, a1;
            #pragma unroll
            for (int j = 0; j < 16; ++j) {
                float v = (av[j] - st.x) * st.y * gs[k0+kc+j] + bs[k0+kc+j];
                if (j < 8) a0[j] = f2bs(v); else a1[j-8] = f2bs(v);
            }
            *(short8*)&As[r*LDK + kc]     = a0;
            *(short8*)&As[r*LDK + kc + 8] = a1;
            int gc = col0 + r;
            const short8* pb = (const short8*)(Wt + (size_t)gc*K + k0 + kc);
            *(short8*)&Bs[r*LDK + kc]     = pb[0];
            *(short8*)&Bs[r*LDK + kc + 8] = pb[1];
        }
        __syncthreads();
        #pragma unroll
        for (int kb = 0; kb < 64; kb += 32) {
            short8 af[4], bfr[4];
            #pragma unroll
            for (int mi = 0; mi < 4; ++mi)
                af[mi] = *(const short8*)&As[(wm*64 + mi*16 + l16)*LDK + kb + quad*8];
            #pragma unroll
            for (int ni = 0; ni < 4; ++ni)
                bfr[ni] = *(const short8*)&Bs[(wn*64 + ni*16 + l16)*LDK + kb + quad*8];
            #pragma unroll
            for (int mi = 0; mi < 4; ++mi)
                #pragma unroll
                for (int ni = 0; ni < 4; ++ni)
                    acc[mi][ni] = __builtin_amdgcn_mfma_f32_16x16x32_bf16(
                        af[mi], bfr[ni], acc[mi][ni], 0, 0, 0);
        }
        __syncthreads();
    }
    #pragma unroll
    for (int mi = 0; mi < 4; ++mi) {
        int rbase = row0 + wm*64 + mi*16 + quad*4;
        #pragma unroll
        for (int ni = 0; ni < 4; ++ni) {
            int c = col0 + wn*64 + ni*16 + l16;
            float bv = bias[c];
            #pragma unroll
            for (int r2 = 0; r2 < 4; ++r2)
                C[(size_t)(rbase + r2)*N + c] = __float2bfloat16(acc[mi][ni][r2] + bv);
        }
    }
}

// ---------- attention stage 1: S = (Q*scale) @ K^T, bf16, cols padded to 1024 ----------
__global__ __launch_bounds__(256) void sattn_kernel(const short* __restrict__ qkv,
                                                    short* __restrict__ S, int half){
    int hh = blockIdx.z;
    int nh = half*16 + hh;
    int n = nh >> 3, h = nh & 7;
    int q0 = blockIdx.x * 64, k0 = blockIdx.y * 64;
    __shared__ short As[64*40];
    __shared__ short Bs[64*40];
    int tid = threadIdx.x;
    int r = tid >> 2, c = (tid & 3) * 8;
    const short8 z8 = {0,0,0,0,0,0,0,0};
    {
        int gq = q0 + r;
        short8 a = z8;
        if (gq < LQ) {
            short8 s = *(const short8*)(qkv + ((size_t)(n*LQ+gq))*768 + h*32 + c);
            #pragma unroll
            for (int j = 0; j < 8; ++j) a[j] = f2bs(bs2f(s[j]) * ATT_SCALE);
        }
        *(short8*)&As[r*40 + c] = a;
        int gk = k0 + r;
        short8 b = z8;
        if (gk < LQ)
            b = *(const short8*)(qkv + ((size_t)(n*LQ+gk))*768 + 256 + h*32 + c);
        *(short8*)&Bs[r*40 + c] = b;
    }
    __syncthreads();
    int wave = tid >> 6, lane = tid & 63;
    int wm = wave >> 1, wn = wave & 1;
    int quad = lane >> 4, l16 = lane & 15;
    floatx4 acc[2][2];
    #pragma unroll
    for (int mi = 0; mi < 2; ++mi) {
        short8 af = *(const short8*)&As[(wm*32 + mi*16 + l16)*40 + quad*8];
        #pragma unroll
        for (int ni = 0; ni < 2; ++ni) {
            short8 bfr = *(const short8*)&Bs[(wn*32 + ni*16 + l16)*40 + quad*8];
            acc[mi][ni] = __builtin_amdgcn_mfma_f32_16x16x32_bf16(
                af, bfr, (floatx4){0.f,0.f,0.f,0.f}, 0, 0, 0);
        }
    }
    #pragma unroll
    for (int mi = 0; mi < 2; ++mi) {
        int rbase = q0 + wm*32 + mi*16 + quad*4;
        #pragma unroll
        for (int ni = 0; ni < 2; ++ni) {
            int col = k0 + wn*32 + ni*16 + l16;
            #pragma unroll
            for (int r2 = 0; r2 < 4; ++r2) {
                int row = rbase + r2;
                if (row < LQ)
                    S[((size_t)hh*LQ + row)*1024 + col] = f2bs(acc[mi][ni][r2]);
            }
        }
    }
}

// ---------- attention stage 2: per-row (max, 1/sumexp), read-only ----------
__global__ __launch_bounds__(256) void rowstat_kernel(const short* __restrict__ S,
                                                      float2* __restrict__ ml){
    int hh = blockIdx.y;
    int wave = threadIdx.x >> 6, lane = threadIdx.x & 63;
    int q = blockIdx.x*4 + wave;
    const unsigned short* row = (const unsigned short*)(S + ((size_t)hh*LQ + q)*1024);
    int base = lane*16;
    float v[16];
    #pragma unroll
    for (int c = 0; c < 4; ++c) {
        ushort4 u = *(const ushort4*)(row + base + c*4);
        v[c*4]   = bs2f((short)u.x); v[c*4+1] = bs2f((short)u.y);
        v[c*4+2] = bs2f((short)u.z); v[c*4+3] = bs2f((short)u.w);
    }
    float m = -3.0e38f;
    #pragma unroll
    for (int j = 0; j < 16; ++j) if (base + j < LQ) m = fmaxf(m, v[j]);
    #pragma unroll
    for (int o = 32; o; o >>= 1) m = fmaxf(m, __shfl_xor(m, o, 64));
    float s = 0.f;
    #pragma unroll
    for (int j = 0; j < 16; ++j) if (base + j < LQ) s += __expf(v[j] - m);
    #pragma unroll
    for (int o = 32; o; o >>= 1) s += __shfl_xor(s, o, 64);
    if (lane == 0) ml[hh*LQ + q] = make_float2(m, 1.f/s);
}

// ---------- attention stage 3: O = softmax(S) @ V ----------
__global__ __launch_bounds__(256) void pv2_kernel(const short* __restrict__ S,
                                                  const float2* __restrict__ ml,
                                                  const short* __restrict__ qkv,
                                                  float* __restrict__ out, int half){
    int hh = blockIdx.y;
    int nh = half*16 + hh;
    int n = nh >> 3, h = nh & 7;
    int q0 = blockIdx.x * 64;
    __shared__ short Ps[64*72];
    __shared__ short VsT[32*72];
    int tid = threadIdx.x;
    int wave = tid >> 6, lane = tid & 63;
    int quad = lane >> 4, l16 = lane & 15;
    int r = tid >> 2;
    int cp = (tid & 3) * 16;
    int cv = (tid & 3) * 8;
    const short8 z8 = {0,0,0,0,0,0,0,0};
    floatx4 acc[2];
    acc[0] = (floatx4){0.f,0.f,0.f,0.f};
    acc[1] = (floatx4){0.f,0.f,0.f,0.f};

    int gq = q0 + r;
    float mrow = 0.f, invl = 0.f;
    bool rok = gq < LQ;
    if (rok) { float2 t = ml[hh*LQ + gq]; mrow = t.x; invl = t.y; }

    for (int k0 = 0; k0 < 1024; k0 += 64) {
        short8 q0v = z8, q1v = z8;
        if (rok) {
            const short* sp = S + ((size_t)hh*LQ + gq)*1024 + k0 + cp;
            short8 p0 = *(const short8*)sp;
            short8 p1 = *(const short8*)(sp + 8);
            #pragma unroll
            for (int j = 0; j < 8; ++j) {
                int c0 = k0 + cp + j, c1 = c0 + 8;
                float pv0 = (c0 < LQ) ? __expf(bs2f(p0[j]) - mrow) * invl : 0.f;
                float pv1 = (c1 < LQ) ? __expf(bs2f(p1[j]) - mrow) * invl : 0.f;
                q0v[j] = f2bs(pv0); q1v[j] = f2bs(pv1);
            }
        }
        *(short8*)&Ps[r*72 + cp]     = q0v;
        *(short8*)&Ps[r*72 + cp + 8] = q1v;
        int gk = k0 + r;
        short8 vv = z8;
        if (gk < LQ)
            vv = *(const short8*)(qkv + ((size_t)(n*LQ+gk))*768 + 512 + h*32 + cv);
        #pragma unroll
        for (int j = 0; j < 8; ++j) VsT[(cv+j)*72 + r] = vv[j];
        __syncthreads();
        #pragma unroll
        for (int kb = 0; kb < 64; kb += 32) {
            short8 af = *(const short8*)&Ps[(wave*16 + l16)*72 + kb + quad*8];
            #pragma unroll
            for (int ni = 0; ni < 2; ++ni) {
                short8 bfr = *(const short8*)&VsT[(ni*16 + l16)*72 + kb + quad*8];
                acc[ni] = __builtin_amdgcn_mfma_f32_16x16x32_bf16(af, bfr, acc[ni], 0, 0, 0);
            }
        }
        __syncthreads();
    }
    #pragma unroll
    for (int ni = 0; ni < 2; ++ni)
        #pragma unroll
        for (int r2 = 0; r2 < 4; ++r2) {
            int row = q0 + wave*16 + quad*4 + r2;
            if (row < LQ)
                out[((size_t)(n*LQ+row))*256 + h*32 + ni*16 + l16] = acc[ni][r2];
        }
}

// ---------- deformable sampling: branch-free clamped corners ----------
__global__ __launch_bounds__(256) void sample2_kernel(
        const bf16* __restrict__ value, const float* __restrict__ offaw,
        const float* __restrict__ cp, float* __restrict__ out){
    int nq = blockIdx.x;
    int n = nq / LQ;
    int d = threadIdx.x & 31, h = threadIdx.x >> 5;
    float cx = cp[nq*2], cy = cp[nq*2+1];
    const float* rowp = offaw + (size_t)nq*480;
    float o0 = rowp[h*40 + d];
    float o1 = (d < 8) ? rowp[h*40 + 32 + d] : 0.f;
    float logit = (d < 20) ? rowp[320 + h*20 + d] : -3.0e38f;
    float mx = logit;
    #pragma unroll
    for (int off = 16; off; off >>= 1) mx = fmaxf(mx, __shfl_xor(mx, off, 32));
    float p = (d < 20) ? __expf(logit - mx) : 0.f;
    float sm = p;
    #pragma unroll
    for (int off = 16; off; off >>= 1) sm += __shfl_xor(sm, off, 32);
    p *= (1.f / sm);

    const int HW[5] = {128,64,32,16,8};
    const int ST[5] = {0,16384,20480,21504,21760};
    float acc = 0.f;
    #pragma unroll
    for (int l = 0; l < 5; ++l) {
        int hw = HW[l];
        float fhw = (float)hw;
        size_t vb = ((size_t)n*LIN + ST[l]) * 256 + h*32 + d;
        #pragma unroll
        for (int pi = 0; pi < 4; ++pi) {
            const int idx = l*4 + pi;
            float w  = __shfl(p, idx, 32);
            float ox = (2*idx < 32)   ? __shfl(o0, 2*idx, 32)   : __shfl(o1, 2*idx-32, 32);
            float oy = (2*idx+1 < 32) ? __shfl(o0, 2*idx+1, 32) : __shfl(o1, 2*idx+1-32, 32);
            float gx = cx*fhw + ox - 0.5f;
            float gy = cy*fhw + oy - 0.5f;
            float x0f = floorf(gx), y0f = floorf(gy);
            float lx = gx - x0f, ly = gy - y0f;
            int x0 = (int)x0f, y0 = (int)y0f;
            int x1 = x0 + 1, y1 = y0 + 1;
            bool bx0 = (unsigned)x0 < (unsigned)hw, bx1 = (unsigned)x1 < (unsigned)hw;
            bool by0 = (unsigned)y0 < (unsigned)hw, by1 = (unsigned)y1 < (unsigned)hw;
            int x0c = min(max(x0, 0), hw-1), x1c = min(max(x1, 0), hw-1);
            int y0c = min(max(y0, 0), hw-1), y1c = min(max(y1, 0), hw-1);
            // unconditional clamped loads (stream through memory pipe, no exec-mask churn)
            float v00 = __bfloat162float(value[vb + (size_t)(y0c*hw + x0c)*256]);
            float v01 = __bfloat162float(value[vb + (size_t)(y0c*hw + x1c)*256]);
            float v10 = __bfloat162float(value[vb + (size_t)(y1c*hw + x0c)*256]);
            float v11 = __bfloat162float(value[vb + (size_t)(y1c*hw + x1c)*256]);
            float w00 = (bx0 && by0) ? (1.f-ly)*(1.f-lx)*w : 0.f;
            float w01 = (bx1 && by0) ? (1.f-ly)*lx*w       : 0.f;
            float w10 = (bx0 && by1) ? ly*(1.f-lx)*w       : 0.f;
            float w11 = (bx1 && by1) ? ly*lx*w             : 0.f;
            acc = fmaf(w00, v00, acc);
            acc = fmaf(w01, v01, acc);
            acc = fmaf(w10, v10, acc);
            acc = fmaf(w11, v11, acc);
        }
    }
    out[(size_t)nq*256 + h*32 + d] = acc;
}

// ---------- final store ----------
__global__ void final_kernel(const float* __restrict__ in, void* __restrict__ out,
                             int n, const int* __restrict__ flag){
    int f = flag[0];
    int i = blockIdx.x*256 + threadIdx.x;
    if (i >= n) return;
    float v = in[i];
    if (!isfinite(v)) v = 0.f;
    if (f) ((float*)out)[i] = v;
    else   ((bf16*)out)[i] = __float2bfloat16(v);
}

extern "C" void kernel_launch(void* const* d_in, const int* in_sizes, int n_in,
                              void* d_out, int out_size, void* d_ws, size_t ws_size,
                              hipStream_t stream){
    const void* x_raw  = d_in[0];
    const void* src    = d_in[1];
    const void* cp_raw = d_in[2];
    char* ws = (char*)d_ws;
    size_t off = 0;
    auto alloc = [&](size_t bytes){ size_t p = off; off += (bytes + 255) & ~(size_t)255; return p; };
    int*   flag  = (int*)(ws + alloc(256));
    float* xf    = (float*)(ws + alloc((size_t)ROWS_X*DIM*4));
    float* pe    = (float*)(ws + alloc((size_t)ROWS_X*DIM*4));
    float* tmp   = (float*)(ws + alloc((size_t)ROWS_X*DIM*4));
    bf16*  qkv   = (bf16*)(ws + alloc((size_t)ROWS_X*768*2));
    bf16*  ffh   = (bf16*)(ws + alloc((size_t)ROWS_X*MLPD*2));
    float* offaw = (float*)(ws + alloc((size_t)ROWS_X*480*4));
    float2* stats = (float2*)(ws + alloc((size_t)ROWS_SRC*8));
    float2* xst  = (float2*)(ws + alloc((size_t)ROWS_X*8));
    float* cpf   = (float*)(ws + alloc((size_t)ROWS_X*2*4));
    float* oab   = (float*)(ws + alloc((size_t)2*480*4));
    float2* ml   = (float2*)(ws + alloc((size_t)16*LQ*8));
    const int sidx[13] = {5,6,7,8,11,12,13,19,21,22,23,25,27};
    const int ssz[13]  = {512,256,512,512,512,512,512,512,512,512,512,1024,512};
    float* sp[13];
    for (int j = 0; j < 13; ++j) sp[j] = (float*)(ws + alloc((size_t)ssz[j]*4));
    short* qkvT = (short*)(ws + alloc((size_t)2*768*256*2));
    short* outT = (short*)(ws + alloc((size_t)2*256*256*2));
    short* oawT = (short*)(ws + alloc((size_t)2*480*256*2));
    short* valT = (short*)(ws + alloc((size_t)2*256*256*2));
    short* opT  = (short*)(ws + alloc((size_t)2*256*256*2));
    short* ff1T = (short*)(ws + alloc((size_t)2*512*256*2));
    short* ff2T = (short*)(ws + alloc((size_t)2*256*512*2));
    bf16*  val  = (bf16*)(ws + alloc((size_t)ROWS_SRC*DIM*2));
    // S (16 nh x 1000 x 1024 bf16 = 31.25 MB) aliases val (44.7 MB): disjoint lifetimes.
    short* Sbuf = (short*)val;
    (void)ws_size; (void)in_sizes; (void)n_in; (void)out_size;

    detect_kernel<<<1, 256, 0, stream>>>(x_raw, flag);
    conv_kernel<<<(ROWS_X*DIM+255)/256, 256, 0, stream>>>(x_raw, xf, ROWS_X*DIM, flag);
    conv_kernel<<<(ROWS_X*2+255)/256, 256, 0, stream>>>(cp_raw, cpf, ROWS_X*2, flag);
    PTab pt;
    for (int j = 0; j < 13; ++j) { pt.src[j] = d_in[sidx[j]]; pt.dst[j] = sp[j]; pt.n[j] = ssz[j]; }
    convs_kernel<<<dim3(4,13), 256, 0, stream>>>(pt, flag);
    catb_kernel<<<dim3(2,2), 256, 0, stream>>>(d_in[15], d_in[17], flag, oab);
    wtrans_kernel<<<dim3(8,24,2), 256, 0, stream>>>(d_in[9],  flag, qkvT, 256, 768, 768, 0);
    wtrans_kernel<<<dim3(8,8,2),  256, 0, stream>>>(d_in[10], flag, outT, 256, 256, 256, 0);
    wtrans_kernel<<<dim3(8,10,2), 256, 0, stream>>>(d_in[14], flag, oawT, 256, 320, 480, 0);
    wtrans_kernel<<<dim3(8,5,2),  256, 0, stream>>>(d_in[16], flag, oawT, 256, 160, 480, 320);
    wtrans_kernel<<<dim3(8,8,2),  256, 0, stream>>>(d_in[18], flag, valT, 256, 256, 256, 0);
    wtrans_kernel<<<dim3(8,8,2),  256, 0, stream>>>(d_in[20], flag, opT,  256, 256, 256, 0);
    wtrans_kernel<<<dim3(8,16,2), 256, 0, stream>>>(d_in[24], flag, ff1T, 256, 512, 512, 0);
    wtrans_kernel<<<dim3(16,8,2), 256, 0, stream>>>(d_in[26], flag, ff2T, 512, 256, 256, 0);

    float* pos_w = sp[0];  float* pos_b = sp[1];
    float* ln1_g = sp[2];  float* ln1_b = sp[3];
    float* out_b = sp[4];
    float* ln2_g = sp[5];  float* ln2_b = sp[6];
    float* val_b = sp[7];  float* op_b  = sp[8];
    float* ln3_g = sp[9];  float* ln3_b = sp[10];
    float* ff_b1 = sp[11]; float* ff_b2 = sp[12];

    pe_kernel<<<ROWS_X, 256, 0, stream>>>(cpf, pos_w, pos_b, pe);
    stats2_kernel<<<ROWS_SRC/4, 256, 0, stream>>>(src, flag, stats);

    int gmx = (ROWS_X + 63) / 64;   // 63
    for (int i = 0; i < 2; ++i) {
        // --- self attention: qkv = LN(xf+pe;ln1) @ qkv_w (LN fused) ---
        xstats_kernel<<<ROWS_X/4, 256, 0, stream>>>(xf, pe, xst);
        mgemm_kernel<3><<<dim3(gmx,12), 256, 0, stream>>>(
            xf, xst, ln1_g + i*DIM, ln1_b + i*DIM, pe, nullptr,
            qkvT + (size_t)i*768*256, nullptr, nullptr, qkv, ROWS_X, 256, 768, 0, 1);
        for (int half = 0; half < 2; ++half) {
            sattn_kernel<<<dim3(16,16,16), 256, 0, stream>>>((const short*)qkv, Sbuf, half);
            rowstat_kernel<<<dim3(250,16), 256, 0, stream>>>(Sbuf, ml);
            pv2_kernel<<<dim3(16,16), 256, 0, stream>>>(Sbuf, ml, (const short*)qkv, tmp, half);
        }
        mgemm_kernel<0><<<dim3(gmx,4), 256, 0, stream>>>(
            tmp, nullptr, nullptr, nullptr, nullptr, nullptr,
            outT + (size_t)i*256*256, out_b + i*DIM, xf, xf, ROWS_X, 256, 256, 0, 0);
        // --- deformable cross attention ---
        mgemm128_kernel<<<dim3(ROWS_SRC/128, 2), 256, 0, stream>>>(
            src, flag, stats, ln2_g + i*DIM, ln2_b + i*DIM,
            valT + (size_t)i*256*256, val_b + i*DIM, val, 256, 256);
        // offaw = (LN(xf;ln2)+pe) @ [off|aw]_w (LN+pe fused)
        xstats_kernel<<<ROWS_X/4, 256, 0, stream>>>(xf, nullptr, xst);
        mgemm_kernel<3><<<dim3(gmx,8), 256, 0, stream>>>(
            xf, xst, ln2_g + i*DIM, ln2_b + i*DIM, nullptr, pe,
            oawT + (size_t)i*480*256, oab + i*480, nullptr, offaw, ROWS_X, 256, 480, 0, 0);
        sample2_kernel<<<ROWS_X, 256, 0, stream>>>(val, offaw, cpf, tmp);
        mgemm_kernel<0><<<dim3(gmx,4), 256, 0, stream>>>(
            tmp, nullptr, nullptr, nullptr, nullptr, nullptr,
            opT + (size_t)i*256*256, op_b + i*DIM, xf, xf, ROWS_X, 256, 256, 0, 0);
        // --- feedforward: ffh = gelu(LN(xf;ln3) @ ff_w1) (LN fused) ---
        xstats_kernel<<<ROWS_X/4, 256, 0, stream>>>(xf, nullptr, xst);
        mgemm_kernel<3><<<dim3(gmx,8), 256, 0, stream>>>(
            xf, xst, ln3_g + i*DIM, ln3_b + i*DIM, nullptr, nullptr,
            ff1T + (size_t)i*512*256, ff_b1 + i*MLPD, nullptr, ffh, ROWS_X, 256, 512, 1, 1);
        mgemm_kernel<2><<<dim3(gmx,4), 256, 0, stream>>>(
            ffh, nullptr, nullptr, nullptr, nullptr, nullptr,
            ff2T + (size_t)i*256*512, ff_b2 + i*DIM, xf, xf, ROWS_X, 512, 256, 0, 0);
    }
    final_kernel<<<(ROWS_X*DIM+255)/256, 256, 0, stream>>>(xf, d_out, ROWS_X*DIM, flag);
}